// Round 6
// baseline (2525.672 us; speedup 1.0000x reference)
//
#include <hip/hip_runtime.h>

// ---------------------------------------------------------------------------
// BiLSTM + CRF on MI355X — R6: force w_hh register residency via asm pin.
// The AMDGPU scheduler's occupancy heuristic re-sinks loop-invariant weight
// loads into the t-loop (R4/R5: VGPR=100, 256KB/step/CU L2 re-stream). An
// asm volatile "+v" pin after the load makes each B value opaque: it cannot
// be rematerialized, and with launch_bounds(512,2) (256-VGPR cap >= ~220
// live) it cannot justify spilling either -> B stays in 128 VGPRs.
// ---------------------------------------------------------------------------

typedef short v8s __attribute__((ext_vector_type(8)));
typedef float v4f __attribute__((ext_vector_type(4)));
typedef int   i4v __attribute__((ext_vector_type(4)));
typedef float v2f __attribute__((ext_vector_type(2)));

__device__ __forceinline__ short f2b(float f){
  unsigned u = __float_as_uint(f);
  u = u + 0x7fffu + ((u >> 16) & 1u);          // RNE
  return (short)(u >> 16);
}
__device__ __forceinline__ float b2f(short s){
  return __uint_as_float(((unsigned)(unsigned short)s) << 16);
}
__device__ __forceinline__ float sigm(float x){ return 1.f/(1.f+__expf(-x)); }
__device__ __forceinline__ float tanh_(float x){ return 1.f - 2.f/(__expf(2.f*x)+1.f); }
__device__ __forceinline__ float sel4(short4 v, int rr){
  return b2f(rr==0 ? v.x : rr==1 ? v.y : rr==2 ? v.z : v.w);
}

// ---------------------------------------------------------------------------
// prep (unchanged from R5)
// ---------------------------------------------------------------------------
__global__ void prep_kernel(const float* wihf, const float* whhf,
                            const float* wihb, const float* whhb,
                            const float* bihf, const float* bhhf,
                            const float* bihb, const float* bhhb,
                            short* wswz, unsigned char* whh8,
                            float* cb, float* em, float* outp)
{
  int gid = blockIdx.x * 256 + threadIdx.x;      // 131072 threads
  if(gid < 65536){
    int mat = gid >> 15;                 // 0 = fwd, 1 = bwd
    int rem = gid & 32767;
    int ct = rem >> 9;
    int kk = (rem >> 6) & 7;
    int lane = rem & 63;
    const float* src = mat ? wihb : wihf;
    int g  = ct*16 + (lane & 15);
    int k0 = kk*32 + (lane >> 4)*8;
    v8s o;
#pragma unroll
    for(int j=0;j<8;j++) o[j] = f2b(src[g*256 + k0 + j]);
    *(v8s*)(wswz + ((long)mat << 18) + ((long)((ct*8+kk)*64 + lane) << 3)) = o;
  } else if(gid < 98304){
    int j2 = gid - 65536;
    int dir = j2 >> 14;
    int rem = j2 & 16383;
    int ct = rem >> 8;
    int kp = (rem >> 6) & 3;
    int lane = rem & 63;
    int lm = lane & 15, lq = lane >> 4;
    const float* src = dir ? whhb : whhf;
    int g = ct*16 + lm;
    i4v ov;
    {
      const float* s = src + g*256 + (2*kp)*32 + lq*8;
      int a0 = __builtin_amdgcn_cvt_pk_fp8_f32(s[0], s[1], 0, 0);
      a0 = __builtin_amdgcn_cvt_pk_fp8_f32(s[2], s[3], a0, 1);
      int a1 = __builtin_amdgcn_cvt_pk_fp8_f32(s[4], s[5], 0, 0);
      a1 = __builtin_amdgcn_cvt_pk_fp8_f32(s[6], s[7], a1, 1);
      ov[0] = a0; ov[1] = a1;
    }
    {
      const float* s = src + g*256 + (2*kp+1)*32 + lq*8;
      int a0 = __builtin_amdgcn_cvt_pk_fp8_f32(s[0], s[1], 0, 0);
      a0 = __builtin_amdgcn_cvt_pk_fp8_f32(s[2], s[3], a0, 1);
      int a1 = __builtin_amdgcn_cvt_pk_fp8_f32(s[4], s[5], 0, 0);
      a1 = __builtin_amdgcn_cvt_pk_fp8_f32(s[6], s[7], a1, 1);
      ov[2] = a0; ov[3] = a1;
    }
    *(i4v*)(whh8 + (long)dir*262144 + ((ct*4+kp)<<10) + lane*16) = ov;
  } else if(gid < 100352){
    int j3 = gid - 98304;
    int dir = j3 >> 10, gg = j3 & 1023;
    cb[j3] = dir ? (bihb[gg] + bhhb[gg]) : (bihf[gg] + bhhf[gg]);
  }
  for(int i=gid; i<589824; i+=131072) em[i] = 0.f;
  if(gid == 0) *outp = 0.f;
}

// ---------------------------------------------------------------------------
// xg_gemm (unchanged from R5)
// ---------------------------------------------------------------------------
__global__ __launch_bounds__(256,2) void xg_gemm(const int* X, const float* emb,
     const short* wswz, const float* cb, short* xg, int t_base, int CT)
{
  int dir = blockIdx.x & 1;
  int tl  = blockIdx.x >> 1;
  int rh  = blockIdx.y;
  int tg  = t_base + tl;
  int tt  = dir ? (511 - tg) : tg;
  __shared__ short a_sh[64*264];
  int tid = threadIdx.x;
  {
    int row = tid >> 2, seg = tid & 3;
    int b = rh*64 + row;
    int idx = X[b*512 + tt];
    const float* erow = emb + (long)idx*256 + seg*64;
    short* dst = a_sh + row*264 + seg*64;
#pragma unroll
    for(int c=0;c<8;c++){
      float4 f0 = ((const float4*)erow)[2*c];
      float4 f1 = ((const float4*)erow)[2*c+1];
      v8s p;
      p[0]=f2b(f0.x); p[1]=f2b(f0.y); p[2]=f2b(f0.z); p[3]=f2b(f0.w);
      p[4]=f2b(f1.x); p[5]=f2b(f1.y); p[6]=f2b(f1.z); p[7]=f2b(f1.w);
      *(v8s*)(dst + c*8) = p;
    }
  }
  __syncthreads();
  int w = tid >> 6, lane = tid & 63, lm = lane & 15, lq = lane >> 4;
  v8s A[4][8];
#pragma unroll
  for(int mt=0;mt<4;mt++)
#pragma unroll
    for(int kk=0;kk<8;kk++)
      A[mt][kk] = *(const v8s*)(a_sh + (mt*16+lm)*264 + kk*32 + lq*8);

  const short* wmat = wswz + ((long)dir << 18);
  const float* cbd  = cb + dir*1024;
  short* xgd = xg + ((long)dir*CT + tl)*131072;

  v8s Bb[2][8];
  {
    const short* bp = wmat + (long)(w*16)*4096 + lane*8;
#pragma unroll
    for(int kk=0;kk<8;kk++) Bb[0][kk] = *(const v8s*)(bp + kk*512);
  }
#pragma unroll
  for(int ci=0;ci<16;ci++){
    int cur = ci & 1;
    int ct = w*16 + ci;
    if(ci < 15){
      const short* bp = wmat + (long)(ct+1)*4096 + lane*8;
#pragma unroll
      for(int kk=0;kk<8;kk++) Bb[cur^1][kk] = *(const v8s*)(bp + kk*512);
    }
    float bias = cbd[ct*16 + lm];
    v4f acc[4];
#pragma unroll
    for(int mt=0;mt<4;mt++) acc[mt] = (v4f){bias,bias,bias,bias};
#pragma unroll
    for(int kk=0;kk<8;kk++)
#pragma unroll
      for(int mt=0;mt<4;mt++)
        acc[mt] = __builtin_amdgcn_mfma_f32_16x16x32_bf16(A[mt][kk], Bb[cur][kk], acc[mt], 0,0,0);
#pragma unroll
    for(int mt=0;mt<4;mt++){
      int r = rh*4 + mt;
      long off = (long)r*16384 + ct*256 + lane*4;
      short4 s4;
      s4.x = f2b(acc[mt][0]); s4.y = f2b(acc[mt][1]);
      s4.z = f2b(acc[mt][2]); s4.w = f2b(acc[mt][3]);
      *(short4*)(xgd + off) = s4;
    }
  }
}

// ---------------------------------------------------------------------------
// lstm_scan: 16 wgs (dir x rowgroup of 16 rows), 512 thr (8 waves).
// B[32] (this wave's full 32KB fp8 w_hh slice) is loaded once and PINNED in
// VGPRs via asm opacity — the scheduler cannot re-sink the loads, and the
// 256-VGPR cap from launch_bounds(512,2) exceeds live pressure (~220), so
// no spill. Per step: xv loads + A ds_reads + 64 fp8 MFMA + gates + h->LDS.
// ---------------------------------------------------------------------------
__global__ __launch_bounds__(512,2) void lstm_scan(
     const short* __restrict__ xg,
     const unsigned char* __restrict__ whh8,
     unsigned char* __restrict__ hg8,
     float* __restrict__ c_state,
     unsigned char* __restrict__ h_state,
     int first, int CT)
{
  __shared__ unsigned char hbuf[2*4352];
  int wg = blockIdx.x;           // 16
  int dir = wg >> 3, r = wg & 7;
  int tid = threadIdx.x, w = tid >> 6, lane = tid & 63, lm = lane & 15, lq = lane >> 4;
  const unsigned char* __restrict__ whhd = whh8 + (long)dir*262144;

  // ---- load this wave's full w_hh slice into registers (128 VGPRs) ----
  i4v B[32];
#pragma unroll
  for(int cid=0; cid<32; cid++){
    int grp = cid>>3, pp = (cid>>2)&1, kp = cid&3;
    int ct = grp*16 + 2*w + pp;
    B[cid] = *(const i4v*)(whhd + ((ct*4+kp)<<10) + lane*16);
  }
  // pin: values become opaque asm outputs — cannot be rematerialized by
  // re-loading; must live in VGPRs across the whole t-loop.
#pragma unroll
  for(int cid=0; cid<32; cid++)
    asm volatile("" : "+v"(B[cid]));

  float c[8];
  if(first){
    for(int i=tid; i<8704; i+=512) hbuf[i] = 0;
#pragma unroll
    for(int i=0;i<8;i++) c[i] = 0.f;
  } else {
    int row = tid >> 5, dc = tid & 31;
    *(long*)(hbuf + row*272 + dc*8) = *(const long*)(h_state + wg*4096 + row*256 + dc*8);
#pragma unroll
    for(int i=0;i<8;i++) c[i] = c_state[(wg*512 + tid)*8 + i];
  }
  __syncthreads();

  int p = 0;
  for(int tl=0; tl<CT; tl++){
    const short* __restrict__ xgt = xg + ((long)dir*CT + tl)*131072 + (long)r*16384 + lane*4;
    short4 xv[8];
#pragma unroll
    for(int ci=0;ci<8;ci++){
      int grp = ci >> 1, pp = ci & 1;
      int ct = grp*16 + 2*w + pp;
      xv[ci] = *(const short4*)(xgt + ct*256);
    }
    const unsigned char* hb = hbuf + p*4352;
    long A[8];
#pragma unroll
    for(int kk=0;kk<8;kk++)
      A[kk] = *(const long*)(hb + lm*272 + kk*32 + lq*8);

    v4f acc[8];
#pragma unroll
    for(int ci=0;ci<8;ci++) acc[ci] = (v4f){0.f,0.f,0.f,0.f};

#pragma unroll
    for(int grp=0;grp<4;grp++){
#pragma unroll
      for(int kk=0;kk<8;kk++){
        union { i4v v; long l[2]; } u0, u1;
        u0.v = B[grp*8 + (kk>>1)];        // pp = 0
        u1.v = B[grp*8 + 4 + (kk>>1)];    // pp = 1
        acc[2*grp]   = __builtin_amdgcn_mfma_f32_16x16x32_fp8_fp8(A[kk], u0.l[kk&1], acc[2*grp],   0,0,0);
        acc[2*grp+1] = __builtin_amdgcn_mfma_f32_16x16x32_fp8_fp8(A[kk], u1.l[kk&1], acc[2*grp+1], 0,0,0);
      }
    }
    unsigned char* hnew = hbuf + (p^1)*4352;
#pragma unroll
    for(int pp=0;pp<2;pp++){
      int d = 32*w + pp*16 + lm;
      float hv[4];
#pragma unroll
      for(int rr=0;rr<4;rr++){
        float ig = acc[0+pp][rr] + sel4(xv[0+pp], rr);
        float fg = acc[2+pp][rr] + sel4(xv[2+pp], rr);
        float gg = acc[4+pp][rr] + sel4(xv[4+pp], rr);
        float og = acc[6+pp][rr] + sel4(xv[6+pp], rr);
        int ix = pp*4 + rr;
        float cn = sigm(fg)*c[ix] + sigm(ig)*tanh_(gg);
        c[ix] = cn;
        hv[rr] = sigm(og)*tanh_(cn);
      }
      int packed = __builtin_amdgcn_cvt_pk_fp8_f32(hv[0], hv[1], 0, 0);
      packed = __builtin_amdgcn_cvt_pk_fp8_f32(hv[2], hv[3], packed, 1);
#pragma unroll
      for(int rr=0;rr<4;rr++)
        hnew[(lq*4+rr)*272 + d] = (unsigned char)((packed >> (8*rr)) & 0xff);
    }
    __syncthreads();
    {
      int row = tid >> 5, dc = tid & 31;
      *(long*)(hg8 + ((long)dir*CT + tl)*32768 + (r*16+row)*256 + dc*8)
        = *(const long*)(hnew + row*272 + dc*8);
    }
    p ^= 1;
  }
  // persist state for next chunk
  {
    int row = tid >> 5, dc = tid & 31;
    const unsigned char* hb = hbuf + p*4352;
    *(long*)(h_state + wg*4096 + row*256 + dc*8) = *(const long*)(hb + row*272 + dc*8);
#pragma unroll
    for(int i=0;i<8;i++) c_state[(wg*512 + tid)*8 + i] = c[i];
  }
}

// ---------------------------------------------------------------------------
// emiss_partial (unchanged)
// ---------------------------------------------------------------------------
__global__ void emiss_partial(const unsigned char* hg8, const float* lin_w,
                              float* em, int t_base, int CT)
{
  int dir = blockIdx.y;
  int wv  = blockIdx.x*4 + (threadIdx.x >> 6);
  int lane = threadIdx.x & 63;
  int tl = wv >> 7, b = wv & 127;
  int s = dir ? (511 - (t_base + tl)) : (t_base + tl);
  int v = *(const int*)(hg8 + ((long)dir*CT + tl)*32768 + b*256 + lane*4);
  v2f lo = __builtin_amdgcn_cvt_pk_f32_fp8(v, 0);
  v2f hi = __builtin_amdgcn_cvt_pk_f32_fp8(v, 1);
  float x0 = lo[0], x1 = lo[1], x2 = hi[0], x3 = hi[1];
  const float* wbase = lin_w + dir*256 + lane*4;
  float part[9];
#pragma unroll
  for(int j=0;j<9;j++){
    float4 wf = *(const float4*)(wbase + j*512);
    part[j] = x0*wf.x + x1*wf.y + x2*wf.z + x3*wf.w;
  }
#pragma unroll
  for(int j=0;j<9;j++){
    float vv = part[j];
#pragma unroll
    for(int off=32; off>0; off>>=1) vv += __shfl_down(vv, off);
    if(lane == 0) em[((long)b*512 + s)*9 + j] += vv;
  }
}

// ---------------------------------------------------------------------------
// CRF (unchanged)
// ---------------------------------------------------------------------------
__global__ void crf_kernel(const float* em, const int* y, const unsigned char* maskb,
                           const float* st, const float* en, const float* tr,
                           const float* lin_b, float* out)
{
  int b = blockIdx.x;
  int lane = threadIdx.x;
  bool isb = (maskb[1] != 0);
  int len = 0;
  for(int k=lane; k<512; k+=64){
    unsigned char mv = isb ? maskb[b*512 + k] : maskb[((long)(b*512 + k))*4];
    len += (mv != 0);
  }
#pragma unroll
  for(int off=32; off>0; off>>=1) len += __shfl_xor(len, off);

  const int* yb = y + b*512;
  float np = 0.f;
  for(int t=lane; t<512; t+=64){
    if(t >= 1 && t < len){
      int yp = yb[t-1], yt = yb[t];
      np += tr[yp*9 + yt] + em[((long)b*512 + t)*9 + yt] + lin_b[yt];
    }
  }
#pragma unroll
  for(int off=32; off>0; off>>=1) np += __shfl_xor(np, off);

  int j = lane;
  float alpha = -1e30f;
  float trc[9];
  float lb = (j < 9) ? lin_b[j] : 0.f;
  if(j < 9){
    alpha = st[j] + em[(long)b*512*9 + j] + lb;
#pragma unroll
    for(int i=0;i<9;i++) trc[i] = tr[i*9 + j];
  }
  for(int t=1; t<len; t++){
    float av[9];
#pragma unroll
    for(int i=0;i<9;i++) av[i] = __shfl(alpha, i);
    if(j < 9){
      float m = av[0] + trc[0];
#pragma unroll
      for(int i=1;i<9;i++) m = fmaxf(m, av[i] + trc[i]);
      float ssum = 0.f;
#pragma unroll
      for(int i=0;i<9;i++) ssum += __expf(av[i] + trc[i] - m);
      alpha = m + __logf(ssum) + em[((long)b*512 + t)*9 + j] + lb;
    }
  }
  float aj = (j < 9) ? (alpha + en[j]) : -1e30f;
  float mm = aj;
#pragma unroll
  for(int off=32; off>0; off>>=1) mm = fmaxf(mm, __shfl_xor(mm, off));
  float ee = (j < 9) ? __expf(aj - mm) : 0.f;
#pragma unroll
  for(int off=32; off>0; off>>=1) ee += __shfl_xor(ee, off);
  float den = mm + __logf(ee);
  if(lane == 0){
    int y0 = yb[0];
    float num = np + st[y0] + em[(long)b*512*9 + y0] + lin_b[y0] + en[yb[len-1]];
    atomicAdd(out, num - den);
  }
}

// ---------------------------------------------------------------------------
extern "C" void kernel_launch(void* const* d_in, const int* in_sizes, int n_in,
                              void* d_out, int out_size, void* d_ws, size_t ws_size,
                              hipStream_t stream)
{
  (void)in_sizes; (void)n_in; (void)out_size;
  const int*   X    = (const int*)d_in[0];
  const int*   y    = (const int*)d_in[1];
  const unsigned char* maskb = (const unsigned char*)d_in[2];
  const float* emb  = (const float*)d_in[3];
  const float* wihf = (const float*)d_in[4];
  const float* whhf = (const float*)d_in[5];
  const float* bihf = (const float*)d_in[6];
  const float* bhhf = (const float*)d_in[7];
  const float* wihb = (const float*)d_in[8];
  const float* whhb = (const float*)d_in[9];
  const float* bihb = (const float*)d_in[10];
  const float* bhhb = (const float*)d_in[11];
  const float* lin_w= (const float*)d_in[12];
  const float* lin_b= (const float*)d_in[13];
  const float* st   = (const float*)d_in[14];
  const float* en   = (const float*)d_in[15];
  const float* tr   = (const float*)d_in[16];

  // ws layout (bytes)
  const long FIXED = 4268032L;
  long CT = 256;
  while (CT > 16 && FIXED + CT*589824L > (long)ws_size) CT >>= 1;
  int NC = (int)(512 / CT);

  char* ws = (char*)d_ws;
  short*         wswz = (short*)(ws);                  // 1,048,576 B (bf16 w_ih frags)
  unsigned char* whh8 = (unsigned char*)(ws + 1048576L); //   524,288 B (fp8 w_hh frags)
  float*         cb   = (float*)(ws + 1572864L);       //     8,192 B
  float*         cst  = (float*)(ws + 1581056L);       //   262,144 B
  unsigned char* hst  = (unsigned char*)(ws + 1843200L); //    65,536 B
  float*         em   = (float*)(ws + 1908736L);       // 2,359,296 B
  short*         xg   = (short*)(ws + 4268032L);       // CT*524,288 B
  unsigned char* hg8  = (unsigned char*)(ws + 4268032L + CT*524288L); // CT*65,536 B

  prep_kernel<<<512, 256, 0, stream>>>(wihf, whhf, wihb, whhb,
                                       bihf, bhhf, bihb, bhhb,
                                       wswz, whh8, cb, em, (float*)d_out);
  for(int ck=0; ck<NC; ck++){
    int tb = ck*(int)CT;
    xg_gemm<<<dim3(2*(int)CT, 2), 256, 0, stream>>>(X, emb, wswz, cb, xg, tb, (int)CT);
    lstm_scan<<<16, 512, 0, stream>>>(xg, whh8, hg8, cst, hst, ck==0 ? 1 : 0, (int)CT);
    emiss_partial<<<dim3(32*(int)CT, 2), 256, 0, stream>>>(hg8, lin_w, em, tb, (int)CT);
  }
  crf_kernel<<<128, 64, 0, stream>>>(em, y, maskb, st, en, tr, lin_b, (float*)d_out);
}

// Round 7
// 2264.601 us; speedup vs baseline: 1.1153x; 1.1153x over previous
//
#include <hip/hip_runtime.h>

// ---------------------------------------------------------------------------
// BiLSTM + CRF on MI355X — R7: hybrid w_hh residency in the scan.
//  - 16 chunks/wave (i,f gates) in a 128KB dynamic-LDS slab (RA-proof)
//  - 16 chunks/wave (g,o gates) in 64 pinned VGPRs
//  - amdgpu_waves_per_eu(1,2): RA budget 256 VGPRs -> no scratch spill
// R6 forensics: asm pin stopped remat but RA (budget ~128) spilled B to
// scratch, which L2-caches -> identical cost to the L2 stream (VGPR 112,
// FETCH flat, time flat). This round removes the >128-reg requirement.
// ---------------------------------------------------------------------------

typedef short v8s __attribute__((ext_vector_type(8)));
typedef float v4f __attribute__((ext_vector_type(4)));
typedef int   i4v __attribute__((ext_vector_type(4)));
typedef float v2f __attribute__((ext_vector_type(2)));

__device__ __forceinline__ short f2b(float f){
  unsigned u = __float_as_uint(f);
  u = u + 0x7fffu + ((u >> 16) & 1u);          // RNE
  return (short)(u >> 16);
}
__device__ __forceinline__ float b2f(short s){
  return __uint_as_float(((unsigned)(unsigned short)s) << 16);
}
__device__ __forceinline__ float sigm(float x){ return 1.f/(1.f+__expf(-x)); }
__device__ __forceinline__ float tanh_(float x){ return 1.f - 2.f/(__expf(2.f*x)+1.f); }
__device__ __forceinline__ float sel4(short4 v, int rr){
  return b2f(rr==0 ? v.x : rr==1 ? v.y : rr==2 ? v.z : v.w);
}

// ---------------------------------------------------------------------------
// prep (unchanged from R6)
// ---------------------------------------------------------------------------
__global__ void prep_kernel(const float* wihf, const float* whhf,
                            const float* wihb, const float* whhb,
                            const float* bihf, const float* bhhf,
                            const float* bihb, const float* bhhb,
                            short* wswz, unsigned char* whh8,
                            float* cb, float* em, float* outp)
{
  int gid = blockIdx.x * 256 + threadIdx.x;      // 131072 threads
  if(gid < 65536){
    int mat = gid >> 15;                 // 0 = fwd, 1 = bwd
    int rem = gid & 32767;
    int ct = rem >> 9;
    int kk = (rem >> 6) & 7;
    int lane = rem & 63;
    const float* src = mat ? wihb : wihf;
    int g  = ct*16 + (lane & 15);
    int k0 = kk*32 + (lane >> 4)*8;
    v8s o;
#pragma unroll
    for(int j=0;j<8;j++) o[j] = f2b(src[g*256 + k0 + j]);
    *(v8s*)(wswz + ((long)mat << 18) + ((long)((ct*8+kk)*64 + lane) << 3)) = o;
  } else if(gid < 98304){
    int j2 = gid - 65536;
    int dir = j2 >> 14;
    int rem = j2 & 16383;
    int ct = rem >> 8;
    int kp = (rem >> 6) & 3;
    int lane = rem & 63;
    int lm = lane & 15, lq = lane >> 4;
    const float* src = dir ? whhb : whhf;
    int g = ct*16 + lm;
    i4v ov;
    {
      const float* s = src + g*256 + (2*kp)*32 + lq*8;
      int a0 = __builtin_amdgcn_cvt_pk_fp8_f32(s[0], s[1], 0, 0);
      a0 = __builtin_amdgcn_cvt_pk_fp8_f32(s[2], s[3], a0, 1);
      int a1 = __builtin_amdgcn_cvt_pk_fp8_f32(s[4], s[5], 0, 0);
      a1 = __builtin_amdgcn_cvt_pk_fp8_f32(s[6], s[7], a1, 1);
      ov[0] = a0; ov[1] = a1;
    }
    {
      const float* s = src + g*256 + (2*kp+1)*32 + lq*8;
      int a0 = __builtin_amdgcn_cvt_pk_fp8_f32(s[0], s[1], 0, 0);
      a0 = __builtin_amdgcn_cvt_pk_fp8_f32(s[2], s[3], a0, 1);
      int a1 = __builtin_amdgcn_cvt_pk_fp8_f32(s[4], s[5], 0, 0);
      a1 = __builtin_amdgcn_cvt_pk_fp8_f32(s[6], s[7], a1, 1);
      ov[2] = a0; ov[3] = a1;
    }
    *(i4v*)(whh8 + (long)dir*262144 + ((ct*4+kp)<<10) + lane*16) = ov;
  } else if(gid < 100352){
    int j3 = gid - 98304;
    int dir = j3 >> 10, gg = j3 & 1023;
    cb[j3] = dir ? (bihb[gg] + bhhb[gg]) : (bihf[gg] + bhhf[gg]);
  }
  for(int i=gid; i<589824; i+=131072) em[i] = 0.f;
  if(gid == 0) *outp = 0.f;
}

// ---------------------------------------------------------------------------
// xg_gemm (unchanged from R6)
// ---------------------------------------------------------------------------
__global__ __launch_bounds__(256,2) void xg_gemm(const int* X, const float* emb,
     const short* wswz, const float* cb, short* xg, int t_base, int CT)
{
  int dir = blockIdx.x & 1;
  int tl  = blockIdx.x >> 1;
  int rh  = blockIdx.y;
  int tg  = t_base + tl;
  int tt  = dir ? (511 - tg) : tg;
  __shared__ short a_sh[64*264];
  int tid = threadIdx.x;
  {
    int row = tid >> 2, seg = tid & 3;
    int b = rh*64 + row;
    int idx = X[b*512 + tt];
    const float* erow = emb + (long)idx*256 + seg*64;
    short* dst = a_sh + row*264 + seg*64;
#pragma unroll
    for(int c=0;c<8;c++){
      float4 f0 = ((const float4*)erow)[2*c];
      float4 f1 = ((const float4*)erow)[2*c+1];
      v8s p;
      p[0]=f2b(f0.x); p[1]=f2b(f0.y); p[2]=f2b(f0.z); p[3]=f2b(f0.w);
      p[4]=f2b(f1.x); p[5]=f2b(f1.y); p[6]=f2b(f1.z); p[7]=f2b(f1.w);
      *(v8s*)(dst + c*8) = p;
    }
  }
  __syncthreads();
  int w = tid >> 6, lane = tid & 63, lm = lane & 15, lq = lane >> 4;
  v8s A[4][8];
#pragma unroll
  for(int mt=0;mt<4;mt++)
#pragma unroll
    for(int kk=0;kk<8;kk++)
      A[mt][kk] = *(const v8s*)(a_sh + (mt*16+lm)*264 + kk*32 + lq*8);

  const short* wmat = wswz + ((long)dir << 18);
  const float* cbd  = cb + dir*1024;
  short* xgd = xg + ((long)dir*CT + tl)*131072;

  v8s Bb[2][8];
  {
    const short* bp = wmat + (long)(w*16)*4096 + lane*8;
#pragma unroll
    for(int kk=0;kk<8;kk++) Bb[0][kk] = *(const v8s*)(bp + kk*512);
  }
#pragma unroll
  for(int ci=0;ci<16;ci++){
    int cur = ci & 1;
    int ct = w*16 + ci;
    if(ci < 15){
      const short* bp = wmat + (long)(ct+1)*4096 + lane*8;
#pragma unroll
      for(int kk=0;kk<8;kk++) Bb[cur^1][kk] = *(const v8s*)(bp + kk*512);
    }
    float bias = cbd[ct*16 + lm];
    v4f acc[4];
#pragma unroll
    for(int mt=0;mt<4;mt++) acc[mt] = (v4f){bias,bias,bias,bias};
#pragma unroll
    for(int kk=0;kk<8;kk++)
#pragma unroll
      for(int mt=0;mt<4;mt++)
        acc[mt] = __builtin_amdgcn_mfma_f32_16x16x32_bf16(A[mt][kk], Bb[cur][kk], acc[mt], 0,0,0);
#pragma unroll
    for(int mt=0;mt<4;mt++){
      int r = rh*4 + mt;
      long off = (long)r*16384 + ct*256 + lane*4;
      short4 s4;
      s4.x = f2b(acc[mt][0]); s4.y = f2b(acc[mt][1]);
      s4.z = f2b(acc[mt][2]); s4.w = f2b(acc[mt][3]);
      *(short4*)(xgd + off) = s4;
    }
  }
}

// ---------------------------------------------------------------------------
// lstm_scan_k<L>: 16 wgs (dir x rowgroup of 16 rows), 512 thr (8 waves).
// Per wave: chunks cid<L in LDS slab (filled once), chunks cid>=L in
// (32-L)*4 pinned VGPRs loaded once. Per step: xv loads + A ds_reads +
// 64 fp8 MFMA (B from LDS/regs) + gates + h fp8 -> LDS dbuf + hg8.
// Dyn LDS: L*8192 (slab) + 8704 (h dbuf).
// ---------------------------------------------------------------------------
template<int L>
__global__ void __launch_bounds__(512)
__attribute__((amdgpu_waves_per_eu(1,2)))
lstm_scan_k(const short* __restrict__ xg,
            const unsigned char* __restrict__ whh8,
            unsigned char* __restrict__ hg8,
            float* __restrict__ c_state,
            unsigned char* __restrict__ h_state,
            int first, int CT)
{
  extern __shared__ unsigned char lds[];
  unsigned char* hbuf = lds + L*8192;
  int wg = blockIdx.x;           // 16
  int dir = wg >> 3, r = wg & 7;
  int tid = threadIdx.x, w = tid >> 6, lane = tid & 63, lm = lane & 15, lq = lane >> 4;
  const unsigned char* __restrict__ whhd = whh8 + (long)dir*262144;
  const unsigned char* slab_w = lds + (w*L)*1024;

  // fill persistent LDS slab: linear ofs == (w2*L + cid)*1024 + inner
#pragma unroll 1
  for(int ofs = tid*16; ofs < L*8192; ofs += 8192){
    int chunk = ofs >> 10;
    int inner = ofs & 1023;
    int w2 = chunk / L;
    int cid = chunk - w2*L;
    int grp = cid>>3, pp=(cid>>2)&1, kp=cid&3;
    int ct = grp*16 + 2*w2 + pp;
    *(i4v*)(lds + ofs) = *(const i4v*)(whhd + ((ct*4+kp)<<10) + inner);
  }

  // register-resident chunks (cid = L..31), loaded once + pinned
  i4v Breg[32-L];
#pragma unroll
  for(int cid=L; cid<32; cid++){
    int grp = cid>>3, pp = (cid>>2)&1, kp = cid&3;
    int ct = grp*16 + 2*w + pp;
    Breg[cid-L] = *(const i4v*)(whhd + ((ct*4+kp)<<10) + lane*16);
  }
#pragma unroll
  for(int cid=0; cid<32-L; cid++)
    asm volatile("" : "+v"(Breg[cid]));

  float c[8];
  if(first){
    for(int i=tid; i<8704; i+=512) hbuf[i] = 0;
#pragma unroll
    for(int i=0;i<8;i++) c[i] = 0.f;
  } else {
    int row = tid >> 5, dc = tid & 31;
    *(long*)(hbuf + row*272 + dc*8) = *(const long*)(h_state + wg*4096 + row*256 + dc*8);
#pragma unroll
    for(int i=0;i<8;i++) c[i] = c_state[(wg*512 + tid)*8 + i];
  }
  __syncthreads();

  int p = 0;
  for(int tl=0; tl<CT; tl++){
    const short* __restrict__ xgt = xg + ((long)dir*CT + tl)*131072 + (long)r*16384 + lane*4;
    short4 xv[8];
#pragma unroll
    for(int ci=0;ci<8;ci++){
      int grp = ci >> 1, pp = ci & 1;
      int ct = grp*16 + 2*w + pp;
      xv[ci] = *(const short4*)(xgt + ct*256);
    }
    const unsigned char* hb = hbuf + p*4352;
    long A[8];
#pragma unroll
    for(int kk=0;kk<8;kk++)
      A[kk] = *(const long*)(hb + lm*272 + kk*32 + lq*8);

    v4f acc[8];
#pragma unroll
    for(int ci=0;ci<8;ci++) acc[ci] = (v4f){0.f,0.f,0.f,0.f};

#pragma unroll
    for(int grp=0;grp<4;grp++){
      i4v Bc[8];
#pragma unroll
      for(int j=0;j<8;j++){
        int cid = grp*8 + j;
        if(cid < L) Bc[j] = *(const i4v*)(slab_w + cid*1024 + lane*16);
        else        Bc[j] = Breg[cid-L];
      }
#pragma unroll
      for(int kk=0;kk<8;kk++){
        union { i4v v; long l[2]; } u0, u1;
        u0.v = Bc[kk>>1];        // pp = 0
        u1.v = Bc[4 + (kk>>1)];  // pp = 1
        acc[2*grp]   = __builtin_amdgcn_mfma_f32_16x16x32_fp8_fp8(A[kk], u0.l[kk&1], acc[2*grp],   0,0,0);
        acc[2*grp+1] = __builtin_amdgcn_mfma_f32_16x16x32_fp8_fp8(A[kk], u1.l[kk&1], acc[2*grp+1], 0,0,0);
      }
    }
    unsigned char* hnew = hbuf + (p^1)*4352;
#pragma unroll
    for(int pp=0;pp<2;pp++){
      int d = 32*w + pp*16 + lm;
      float hv[4];
#pragma unroll
      for(int rr=0;rr<4;rr++){
        float ig = acc[0+pp][rr] + sel4(xv[0+pp], rr);
        float fg = acc[2+pp][rr] + sel4(xv[2+pp], rr);
        float gg = acc[4+pp][rr] + sel4(xv[4+pp], rr);
        float og = acc[6+pp][rr] + sel4(xv[6+pp], rr);
        int ix = pp*4 + rr;
        float cn = sigm(fg)*c[ix] + sigm(ig)*tanh_(gg);
        c[ix] = cn;
        hv[rr] = sigm(og)*tanh_(cn);
      }
      int packed = __builtin_amdgcn_cvt_pk_fp8_f32(hv[0], hv[1], 0, 0);
      packed = __builtin_amdgcn_cvt_pk_fp8_f32(hv[2], hv[3], packed, 1);
#pragma unroll
      for(int rr=0;rr<4;rr++)
        hnew[(lq*4+rr)*272 + d] = (unsigned char)((packed >> (8*rr)) & 0xff);
    }
    __syncthreads();
    {
      int row = tid >> 5, dc = tid & 31;
      *(long*)(hg8 + ((long)dir*CT + tl)*32768 + (r*16+row)*256 + dc*8)
        = *(const long*)(hnew + row*272 + dc*8);
    }
    p ^= 1;
  }
  // persist state for next chunk
  {
    int row = tid >> 5, dc = tid & 31;
    const unsigned char* hb = hbuf + p*4352;
    *(long*)(h_state + wg*4096 + row*256 + dc*8) = *(const long*)(hb + row*272 + dc*8);
#pragma unroll
    for(int i=0;i<8;i++) c_state[(wg*512 + tid)*8 + i] = c[i];
  }
}

// ---------------------------------------------------------------------------
// emiss_partial (unchanged)
// ---------------------------------------------------------------------------
__global__ void emiss_partial(const unsigned char* hg8, const float* lin_w,
                              float* em, int t_base, int CT)
{
  int dir = blockIdx.y;
  int wv  = blockIdx.x*4 + (threadIdx.x >> 6);
  int lane = threadIdx.x & 63;
  int tl = wv >> 7, b = wv & 127;
  int s = dir ? (511 - (t_base + tl)) : (t_base + tl);
  int v = *(const int*)(hg8 + ((long)dir*CT + tl)*32768 + b*256 + lane*4);
  v2f lo = __builtin_amdgcn_cvt_pk_f32_fp8(v, 0);
  v2f hi = __builtin_amdgcn_cvt_pk_f32_fp8(v, 1);
  float x0 = lo[0], x1 = lo[1], x2 = hi[0], x3 = hi[1];
  const float* wbase = lin_w + dir*256 + lane*4;
  float part[9];
#pragma unroll
  for(int j=0;j<9;j++){
    float4 wf = *(const float4*)(wbase + j*512);
    part[j] = x0*wf.x + x1*wf.y + x2*wf.z + x3*wf.w;
  }
#pragma unroll
  for(int j=0;j<9;j++){
    float vv = part[j];
#pragma unroll
    for(int off=32; off>0; off>>=1) vv += __shfl_down(vv, off);
    if(lane == 0) em[((long)b*512 + s)*9 + j] += vv;
  }
}

// ---------------------------------------------------------------------------
// CRF (unchanged)
// ---------------------------------------------------------------------------
__global__ void crf_kernel(const float* em, const int* y, const unsigned char* maskb,
                           const float* st, const float* en, const float* tr,
                           const float* lin_b, float* out)
{
  int b = blockIdx.x;
  int lane = threadIdx.x;
  bool isb = (maskb[1] != 0);
  int len = 0;
  for(int k=lane; k<512; k+=64){
    unsigned char mv = isb ? maskb[b*512 + k] : maskb[((long)(b*512 + k))*4];
    len += (mv != 0);
  }
#pragma unroll
  for(int off=32; off>0; off>>=1) len += __shfl_xor(len, off);

  const int* yb = y + b*512;
  float np = 0.f;
  for(int t=lane; t<512; t+=64){
    if(t >= 1 && t < len){
      int yp = yb[t-1], yt = yb[t];
      np += tr[yp*9 + yt] + em[((long)b*512 + t)*9 + yt] + lin_b[yt];
    }
  }
#pragma unroll
  for(int off=32; off>0; off>>=1) np += __shfl_xor(np, off);

  int j = lane;
  float alpha = -1e30f;
  float trc[9];
  float lb = (j < 9) ? lin_b[j] : 0.f;
  if(j < 9){
    alpha = st[j] + em[(long)b*512*9 + j] + lb;
#pragma unroll
    for(int i=0;i<9;i++) trc[i] = tr[i*9 + j];
  }
  for(int t=1; t<len; t++){
    float av[9];
#pragma unroll
    for(int i=0;i<9;i++) av[i] = __shfl(alpha, i);
    if(j < 9){
      float m = av[0] + trc[0];
#pragma unroll
      for(int i=1;i<9;i++) m = fmaxf(m, av[i] + trc[i]);
      float ssum = 0.f;
#pragma unroll
      for(int i=0;i<9;i++) ssum += __expf(av[i] + trc[i] - m);
      alpha = m + __logf(ssum) + em[((long)b*512 + t)*9 + j] + lb;
    }
  }
  float aj = (j < 9) ? (alpha + en[j]) : -1e30f;
  float mm = aj;
#pragma unroll
  for(int off=32; off>0; off>>=1) mm = fmaxf(mm, __shfl_xor(mm, off));
  float ee = (j < 9) ? __expf(aj - mm) : 0.f;
#pragma unroll
  for(int off=32; off>0; off>>=1) ee += __shfl_xor(ee, off);
  float den = mm + __logf(ee);
  if(lane == 0){
    int y0 = yb[0];
    float num = np + st[y0] + em[(long)b*512*9 + y0] + lin_b[y0] + en[yb[len-1]];
    atomicAdd(out, num - den);
  }
}

// ---------------------------------------------------------------------------
extern "C" void kernel_launch(void* const* d_in, const int* in_sizes, int n_in,
                              void* d_out, int out_size, void* d_ws, size_t ws_size,
                              hipStream_t stream)
{
  (void)in_sizes; (void)n_in; (void)out_size;
  const int*   X    = (const int*)d_in[0];
  const int*   y    = (const int*)d_in[1];
  const unsigned char* maskb = (const unsigned char*)d_in[2];
  const float* emb  = (const float*)d_in[3];
  const float* wihf = (const float*)d_in[4];
  const float* whhf = (const float*)d_in[5];
  const float* bihf = (const float*)d_in[6];
  const float* bhhf = (const float*)d_in[7];
  const float* wihb = (const float*)d_in[8];
  const float* whhb = (const float*)d_in[9];
  const float* bihb = (const float*)d_in[10];
  const float* bhhb = (const float*)d_in[11];
  const float* lin_w= (const float*)d_in[12];
  const float* lin_b= (const float*)d_in[13];
  const float* st   = (const float*)d_in[14];
  const float* en   = (const float*)d_in[15];
  const float* tr   = (const float*)d_in[16];

  // ws layout (bytes)
  const long FIXED = 4268032L;
  long CT = 256;
  while (CT > 16 && FIXED + CT*589824L > (long)ws_size) CT >>= 1;
  int NC = (int)(512 / CT);

  char* ws = (char*)d_ws;
  short*         wswz = (short*)(ws);                  // 1,048,576 B (bf16 w_ih frags)
  unsigned char* whh8 = (unsigned char*)(ws + 1048576L); //   524,288 B (fp8 w_hh frags)
  float*         cb   = (float*)(ws + 1572864L);       //     8,192 B
  float*         cst  = (float*)(ws + 1581056L);       //   262,144 B
  unsigned char* hst  = (unsigned char*)(ws + 1843200L); //    65,536 B
  float*         em   = (float*)(ws + 1908736L);       // 2,359,296 B
  short*         xg   = (short*)(ws + 4268032L);       // CT*524,288 B
  unsigned char* hg8  = (unsigned char*)(ws + 4268032L + CT*524288L); // CT*65,536 B

  const int LDS16 = 16*8192 + 8704;   // 139,776 B
  const int LDS6  = 6*8192 + 8704;    //  57,856 B
  bool big = (hipFuncSetAttribute(reinterpret_cast<const void*>(&lstm_scan_k<16>),
              hipFuncAttributeMaxDynamicSharedMemorySize, LDS16) == hipSuccess);

  prep_kernel<<<512, 256, 0, stream>>>(wihf, whhf, wihb, whhb,
                                       bihf, bhhf, bihb, bhhb,
                                       wswz, whh8, cb, em, (float*)d_out);
  for(int ck=0; ck<NC; ck++){
    int tb = ck*(int)CT;
    xg_gemm<<<dim3(2*(int)CT, 2), 256, 0, stream>>>(X, emb, wswz, cb, xg, tb, (int)CT);
    if(big)
      lstm_scan_k<16><<<16, 512, LDS16, stream>>>(xg, whh8, hg8, cst, hst, ck==0 ? 1 : 0, (int)CT);
    else
      lstm_scan_k<6><<<16, 512, LDS6, stream>>>(xg, whh8, hg8, cst, hst, ck==0 ? 1 : 0, (int)CT);
    emiss_partial<<<dim3(32*(int)CT, 2), 256, 0, stream>>>(hg8, lin_w, em, tb, (int)CT);
  }
  crf_kernel<<<128, 64, 0, stream>>>(em, y, maskb, st, en, tr, lin_b, (float*)d_out);
}

// Round 8
// 2218.261 us; speedup vs baseline: 1.1386x; 1.0209x over previous
//
#include <hip/hip_runtime.h>

// ---------------------------------------------------------------------------
// BiLSTM + CRF on MI355X — R8: scan restructured to fit the RA's 128-VGPR
// budget. 16 waves/wg (1024 thr); each wave owns 4 col-tiles (one per gate)
// => w_hh slice = 16 chunks = 64 VGPRs, pinned; peak live ~123 <= 128 so the
// pin is satisfiable WITHOUT scratch spill (R5-R7 forensics: RA budget ~128
// is immovable; pinning >64-reg slices just converts to scratch reloads).
// Zero per-step weight traffic; h fp8 in LDS dbuf; one barrier/step.
// ---------------------------------------------------------------------------

typedef short v8s __attribute__((ext_vector_type(8)));
typedef float v4f __attribute__((ext_vector_type(4)));
typedef int   i4v __attribute__((ext_vector_type(4)));
typedef float v2f __attribute__((ext_vector_type(2)));

__device__ __forceinline__ short f2b(float f){
  unsigned u = __float_as_uint(f);
  u = u + 0x7fffu + ((u >> 16) & 1u);          // RNE
  return (short)(u >> 16);
}
__device__ __forceinline__ float b2f(short s){
  return __uint_as_float(((unsigned)(unsigned short)s) << 16);
}
__device__ __forceinline__ float sigm(float x){ return 1.f/(1.f+__expf(-x)); }
__device__ __forceinline__ float tanh_(float x){ return 1.f - 2.f/(__expf(2.f*x)+1.f); }
__device__ __forceinline__ float sel4(short4 v, int rr){
  return b2f(rr==0 ? v.x : rr==1 ? v.y : rr==2 ? v.z : v.w);
}

// ---------------------------------------------------------------------------
// prep (unchanged from R7)
// ---------------------------------------------------------------------------
__global__ void prep_kernel(const float* wihf, const float* whhf,
                            const float* wihb, const float* whhb,
                            const float* bihf, const float* bhhf,
                            const float* bihb, const float* bhhb,
                            short* wswz, unsigned char* whh8,
                            float* cb, float* em, float* outp)
{
  int gid = blockIdx.x * 256 + threadIdx.x;      // 131072 threads
  if(gid < 65536){
    int mat = gid >> 15;                 // 0 = fwd, 1 = bwd
    int rem = gid & 32767;
    int ct = rem >> 9;
    int kk = (rem >> 6) & 7;
    int lane = rem & 63;
    const float* src = mat ? wihb : wihf;
    int g  = ct*16 + (lane & 15);
    int k0 = kk*32 + (lane >> 4)*8;
    v8s o;
#pragma unroll
    for(int j=0;j<8;j++) o[j] = f2b(src[g*256 + k0 + j]);
    *(v8s*)(wswz + ((long)mat << 18) + ((long)((ct*8+kk)*64 + lane) << 3)) = o;
  } else if(gid < 98304){
    int j2 = gid - 65536;
    int dir = j2 >> 14;
    int rem = j2 & 16383;
    int ct = rem >> 8;
    int kp = (rem >> 6) & 3;
    int lane = rem & 63;
    int lm = lane & 15, lq = lane >> 4;
    const float* src = dir ? whhb : whhf;
    int g = ct*16 + lm;
    i4v ov;
    {
      const float* s = src + g*256 + (2*kp)*32 + lq*8;
      int a0 = __builtin_amdgcn_cvt_pk_fp8_f32(s[0], s[1], 0, 0);
      a0 = __builtin_amdgcn_cvt_pk_fp8_f32(s[2], s[3], a0, 1);
      int a1 = __builtin_amdgcn_cvt_pk_fp8_f32(s[4], s[5], 0, 0);
      a1 = __builtin_amdgcn_cvt_pk_fp8_f32(s[6], s[7], a1, 1);
      ov[0] = a0; ov[1] = a1;
    }
    {
      const float* s = src + g*256 + (2*kp+1)*32 + lq*8;
      int a0 = __builtin_amdgcn_cvt_pk_fp8_f32(s[0], s[1], 0, 0);
      a0 = __builtin_amdgcn_cvt_pk_fp8_f32(s[2], s[3], a0, 1);
      int a1 = __builtin_amdgcn_cvt_pk_fp8_f32(s[4], s[5], 0, 0);
      a1 = __builtin_amdgcn_cvt_pk_fp8_f32(s[6], s[7], a1, 1);
      ov[2] = a0; ov[3] = a1;
    }
    *(i4v*)(whh8 + (long)dir*262144 + ((ct*4+kp)<<10) + lane*16) = ov;
  } else if(gid < 100352){
    int j3 = gid - 98304;
    int dir = j3 >> 10, gg = j3 & 1023;
    cb[j3] = dir ? (bihb[gg] + bhhb[gg]) : (bihf[gg] + bhhf[gg]);
  }
  for(int i=gid; i<589824; i+=131072) em[i] = 0.f;
  if(gid == 0) *outp = 0.f;
}

// ---------------------------------------------------------------------------
// xg_gemm (unchanged from R7)
// ---------------------------------------------------------------------------
__global__ __launch_bounds__(256,2) void xg_gemm(const int* X, const float* emb,
     const short* wswz, const float* cb, short* xg, int t_base, int CT)
{
  int dir = blockIdx.x & 1;
  int tl  = blockIdx.x >> 1;
  int rh  = blockIdx.y;
  int tg  = t_base + tl;
  int tt  = dir ? (511 - tg) : tg;
  __shared__ short a_sh[64*264];
  int tid = threadIdx.x;
  {
    int row = tid >> 2, seg = tid & 3;
    int b = rh*64 + row;
    int idx = X[b*512 + tt];
    const float* erow = emb + (long)idx*256 + seg*64;
    short* dst = a_sh + row*264 + seg*64;
#pragma unroll
    for(int c=0;c<8;c++){
      float4 f0 = ((const float4*)erow)[2*c];
      float4 f1 = ((const float4*)erow)[2*c+1];
      v8s p;
      p[0]=f2b(f0.x); p[1]=f2b(f0.y); p[2]=f2b(f0.z); p[3]=f2b(f0.w);
      p[4]=f2b(f1.x); p[5]=f2b(f1.y); p[6]=f2b(f1.z); p[7]=f2b(f1.w);
      *(v8s*)(dst + c*8) = p;
    }
  }
  __syncthreads();
  int w = tid >> 6, lane = tid & 63, lm = lane & 15, lq = lane >> 4;
  v8s A[4][8];
#pragma unroll
  for(int mt=0;mt<4;mt++)
#pragma unroll
    for(int kk=0;kk<8;kk++)
      A[mt][kk] = *(const v8s*)(a_sh + (mt*16+lm)*264 + kk*32 + lq*8);

  const short* wmat = wswz + ((long)dir << 18);
  const float* cbd  = cb + dir*1024;
  short* xgd = xg + ((long)dir*CT + tl)*131072;

  v8s Bb[2][8];
  {
    const short* bp = wmat + (long)(w*16)*4096 + lane*8;
#pragma unroll
    for(int kk=0;kk<8;kk++) Bb[0][kk] = *(const v8s*)(bp + kk*512);
  }
#pragma unroll
  for(int ci=0;ci<16;ci++){
    int cur = ci & 1;
    int ct = w*16 + ci;
    if(ci < 15){
      const short* bp = wmat + (long)(ct+1)*4096 + lane*8;
#pragma unroll
      for(int kk=0;kk<8;kk++) Bb[cur^1][kk] = *(const v8s*)(bp + kk*512);
    }
    float bias = cbd[ct*16 + lm];
    v4f acc[4];
#pragma unroll
    for(int mt=0;mt<4;mt++) acc[mt] = (v4f){bias,bias,bias,bias};
#pragma unroll
    for(int kk=0;kk<8;kk++)
#pragma unroll
      for(int mt=0;mt<4;mt++)
        acc[mt] = __builtin_amdgcn_mfma_f32_16x16x32_bf16(A[mt][kk], Bb[cur][kk], acc[mt], 0,0,0);
#pragma unroll
    for(int mt=0;mt<4;mt++){
      int r = rh*4 + mt;
      long off = (long)r*16384 + ct*256 + lane*4;
      short4 s4;
      s4.x = f2b(acc[mt][0]); s4.y = f2b(acc[mt][1]);
      s4.z = f2b(acc[mt][2]); s4.w = f2b(acc[mt][3]);
      *(short4*)(xgd + off) = s4;
    }
  }
}

// ---------------------------------------------------------------------------
// lstm_scan: 16 wgs (dir x rowgroup of 16 rows), 1024 thr = 16 waves.
// Wave w owns col-tiles ct = {grp*16 + w} (one per gate) -> h-dims
// [16w, 16w+16). B slice = 16 chunks = 64 pinned VGPRs, loaded once.
// Peak live ~123 VGPRs <= 128 RA budget -> no spill. Per step:
// 4 xv loads + 8 A ds_reads + 32 fp8 MFMA + lane-local c update +
// h fp8 -> LDS dbuf + hg8 dump; one barrier.
// ---------------------------------------------------------------------------
__global__ __launch_bounds__(1024,1) void lstm_scan(
     const short* __restrict__ xg,
     const unsigned char* __restrict__ whh8,
     unsigned char* __restrict__ hg8,
     float* __restrict__ c_state,
     unsigned char* __restrict__ h_state,
     int first, int CT)
{
  __shared__ unsigned char hbuf[2*4352];
  int wg = blockIdx.x;           // 16
  int dir = wg >> 3, r = wg & 7;
  int tid = threadIdx.x, w = tid >> 6, lane = tid & 63, lm = lane & 15, lq = lane >> 4;
  const unsigned char* __restrict__ whhd = whh8 + (long)dir*262144;

  // ---- load this wave's w_hh slice: 4 ct (i,f,g,o) x 4 kp = 64 VGPRs ----
  i4v B[16];
#pragma unroll
  for(int grp=0; grp<4; grp++)
#pragma unroll
    for(int kp=0; kp<4; kp++){
      int ct = grp*16 + w;
      B[grp*4+kp] = *(const i4v*)(whhd + ((ct*4+kp)<<10) + lane*16);
    }
#pragma unroll
  for(int b=0; b<16; b++)
    asm volatile("" : "+v"(B[b]));

  float c[4];
  if(first){
    for(int i=tid; i<8704; i+=1024) hbuf[i] = 0;
#pragma unroll
    for(int i=0;i<4;i++) c[i] = 0.f;
  } else {
    int row = tid >> 6, col = tid & 63;
    *(int*)(hbuf + row*272 + col*4) = *(const int*)(h_state + wg*4096 + row*256 + col*4);
#pragma unroll
    for(int i=0;i<4;i++) c[i] = c_state[(wg*1024 + tid)*4 + i];
  }
  __syncthreads();

  int p = 0;
  for(int tl=0; tl<CT; tl++){
    const short* __restrict__ xgt = xg + ((long)dir*CT + tl)*131072 + (long)r*16384 + lane*4;
    short4 xv[4];
#pragma unroll
    for(int grp=0;grp<4;grp++)
      xv[grp] = *(const short4*)(xgt + (grp*16 + w)*256);

    const unsigned char* hb = hbuf + p*4352;
    long A[8];
#pragma unroll
    for(int kk=0;kk<8;kk++)
      A[kk] = *(const long*)(hb + lm*272 + kk*32 + lq*8);

    v4f acc[4];
#pragma unroll
    for(int grp=0;grp<4;grp++) acc[grp] = (v4f){0.f,0.f,0.f,0.f};

#pragma unroll
    for(int grp=0;grp<4;grp++){
#pragma unroll
      for(int kk=0;kk<8;kk++){
        union { i4v v; long l[2]; } u;
        u.v = B[grp*4 + (kk>>1)];
        acc[grp] = __builtin_amdgcn_mfma_f32_16x16x32_fp8_fp8(A[kk], u.l[kk&1], acc[grp], 0,0,0);
      }
    }

    unsigned char* hnew = hbuf + (p^1)*4352;
    {
      int d = 16*w + lm;
      float hv[4];
#pragma unroll
      for(int rr=0;rr<4;rr++){
        float ig = acc[0][rr] + sel4(xv[0], rr);
        float fg = acc[1][rr] + sel4(xv[1], rr);
        float gg = acc[2][rr] + sel4(xv[2], rr);
        float og = acc[3][rr] + sel4(xv[3], rr);
        float cn = sigm(fg)*c[rr] + sigm(ig)*tanh_(gg);
        c[rr] = cn;
        hv[rr] = sigm(og)*tanh_(cn);
      }
      int packed = __builtin_amdgcn_cvt_pk_fp8_f32(hv[0], hv[1], 0, 0);
      packed = __builtin_amdgcn_cvt_pk_fp8_f32(hv[2], hv[3], packed, 1);
#pragma unroll
      for(int rr=0;rr<4;rr++)
        hnew[(lq*4+rr)*272 + d] = (unsigned char)((packed >> (8*rr)) & 0xff);
    }
    __syncthreads();
    {
      int row = tid >> 6, col = tid & 63;
      *(int*)(hg8 + ((long)dir*CT + tl)*32768 + (r*16+row)*256 + col*4)
        = *(const int*)(hnew + row*272 + col*4);
    }
    p ^= 1;
  }
  // persist state for next chunk
  {
    int row = tid >> 6, col = tid & 63;
    const unsigned char* hb = hbuf + p*4352;
    *(int*)(h_state + wg*4096 + row*256 + col*4) = *(const int*)(hb + row*272 + col*4);
#pragma unroll
    for(int i=0;i<4;i++) c_state[(wg*1024 + tid)*4 + i] = c[i];
  }
}

// ---------------------------------------------------------------------------
// emiss_partial (unchanged)
// ---------------------------------------------------------------------------
__global__ void emiss_partial(const unsigned char* hg8, const float* lin_w,
                              float* em, int t_base, int CT)
{
  int dir = blockIdx.y;
  int wv  = blockIdx.x*4 + (threadIdx.x >> 6);
  int lane = threadIdx.x & 63;
  int tl = wv >> 7, b = wv & 127;
  int s = dir ? (511 - (t_base + tl)) : (t_base + tl);
  int v = *(const int*)(hg8 + ((long)dir*CT + tl)*32768 + b*256 + lane*4);
  v2f lo = __builtin_amdgcn_cvt_pk_f32_fp8(v, 0);
  v2f hi = __builtin_amdgcn_cvt_pk_f32_fp8(v, 1);
  float x0 = lo[0], x1 = lo[1], x2 = hi[0], x3 = hi[1];
  const float* wbase = lin_w + dir*256 + lane*4;
  float part[9];
#pragma unroll
  for(int j=0;j<9;j++){
    float4 wf = *(const float4*)(wbase + j*512);
    part[j] = x0*wf.x + x1*wf.y + x2*wf.z + x3*wf.w;
  }
#pragma unroll
  for(int j=0;j<9;j++){
    float vv = part[j];
#pragma unroll
    for(int off=32; off>0; off>>=1) vv += __shfl_down(vv, off);
    if(lane == 0) em[((long)b*512 + s)*9 + j] += vv;
  }
}

// ---------------------------------------------------------------------------
// CRF (unchanged)
// ---------------------------------------------------------------------------
__global__ void crf_kernel(const float* em, const int* y, const unsigned char* maskb,
                           const float* st, const float* en, const float* tr,
                           const float* lin_b, float* out)
{
  int b = blockIdx.x;
  int lane = threadIdx.x;
  bool isb = (maskb[1] != 0);
  int len = 0;
  for(int k=lane; k<512; k+=64){
    unsigned char mv = isb ? maskb[b*512 + k] : maskb[((long)(b*512 + k))*4];
    len += (mv != 0);
  }
#pragma unroll
  for(int off=32; off>0; off>>=1) len += __shfl_xor(len, off);

  const int* yb = y + b*512;
  float np = 0.f;
  for(int t=lane; t<512; t+=64){
    if(t >= 1 && t < len){
      int yp = yb[t-1], yt = yb[t];
      np += tr[yp*9 + yt] + em[((long)b*512 + t)*9 + yt] + lin_b[yt];
    }
  }
#pragma unroll
  for(int off=32; off>0; off>>=1) np += __shfl_xor(np, off);

  int j = lane;
  float alpha = -1e30f;
  float trc[9];
  float lb = (j < 9) ? lin_b[j] : 0.f;
  if(j < 9){
    alpha = st[j] + em[(long)b*512*9 + j] + lb;
#pragma unroll
    for(int i=0;i<9;i++) trc[i] = tr[i*9 + j];
  }
  for(int t=1; t<len; t++){
    float av[9];
#pragma unroll
    for(int i=0;i<9;i++) av[i] = __shfl(alpha, i);
    if(j < 9){
      float m = av[0] + trc[0];
#pragma unroll
      for(int i=1;i<9;i++) m = fmaxf(m, av[i] + trc[i]);
      float ssum = 0.f;
#pragma unroll
      for(int i=0;i<9;i++) ssum += __expf(av[i] + trc[i] - m);
      alpha = m + __logf(ssum) + em[((long)b*512 + t)*9 + j] + lb;
    }
  }
  float aj = (j < 9) ? (alpha + en[j]) : -1e30f;
  float mm = aj;
#pragma unroll
  for(int off=32; off>0; off>>=1) mm = fmaxf(mm, __shfl_xor(mm, off));
  float ee = (j < 9) ? __expf(aj - mm) : 0.f;
#pragma unroll
  for(int off=32; off>0; off>>=1) ee += __shfl_xor(ee, off);
  float den = mm + __logf(ee);
  if(lane == 0){
    int y0 = yb[0];
    float num = np + st[y0] + em[(long)b*512*9 + y0] + lin_b[y0] + en[yb[len-1]];
    atomicAdd(out, num - den);
  }
}

// ---------------------------------------------------------------------------
extern "C" void kernel_launch(void* const* d_in, const int* in_sizes, int n_in,
                              void* d_out, int out_size, void* d_ws, size_t ws_size,
                              hipStream_t stream)
{
  (void)in_sizes; (void)n_in; (void)out_size;
  const int*   X    = (const int*)d_in[0];
  const int*   y    = (const int*)d_in[1];
  const unsigned char* maskb = (const unsigned char*)d_in[2];
  const float* emb  = (const float*)d_in[3];
  const float* wihf = (const float*)d_in[4];
  const float* whhf = (const float*)d_in[5];
  const float* bihf = (const float*)d_in[6];
  const float* bhhf = (const float*)d_in[7];
  const float* wihb = (const float*)d_in[8];
  const float* whhb = (const float*)d_in[9];
  const float* bihb = (const float*)d_in[10];
  const float* bhhb = (const float*)d_in[11];
  const float* lin_w= (const float*)d_in[12];
  const float* lin_b= (const float*)d_in[13];
  const float* st   = (const float*)d_in[14];
  const float* en   = (const float*)d_in[15];
  const float* tr   = (const float*)d_in[16];

  // ws layout (bytes)
  const long FIXED = 4268032L;
  long CT = 256;
  while (CT > 16 && FIXED + CT*589824L > (long)ws_size) CT >>= 1;
  int NC = (int)(512 / CT);

  char* ws = (char*)d_ws;
  short*         wswz = (short*)(ws);                  // 1,048,576 B (bf16 w_ih frags)
  unsigned char* whh8 = (unsigned char*)(ws + 1048576L); //   524,288 B (fp8 w_hh frags)
  float*         cb   = (float*)(ws + 1572864L);       //     8,192 B
  float*         cst  = (float*)(ws + 1581056L);       //   262,144 B
  unsigned char* hst  = (unsigned char*)(ws + 1843200L); //    65,536 B
  float*         em   = (float*)(ws + 1908736L);       // 2,359,296 B
  short*         xg   = (short*)(ws + 4268032L);       // CT*524,288 B
  unsigned char* hg8  = (unsigned char*)(ws + 4268032L + CT*524288L); // CT*65,536 B

  prep_kernel<<<512, 256, 0, stream>>>(wihf, whhf, wihb, whhb,
                                       bihf, bhhf, bihb, bhhb,
                                       wswz, whh8, cb, em, (float*)d_out);
  for(int ck=0; ck<NC; ck++){
    int tb = ck*(int)CT;
    xg_gemm<<<dim3(2*(int)CT, 2), 256, 0, stream>>>(X, emb, wswz, cb, xg, tb, (int)CT);
    lstm_scan<<<16, 1024, 0, stream>>>(xg, whh8, hg8, cst, hst, ck==0 ? 1 : 0, (int)CT);
    emiss_partial<<<dim3(32*(int)CT, 2), 256, 0, stream>>>(hg8, lin_w, em, tb, (int)CT);
  }
  crf_kernel<<<128, 64, 0, stream>>>(em, y, maskb, st, en, tr, lin_b, (float*)d_out);
}

// Round 9
// 2201.462 us; speedup vs baseline: 1.1473x; 1.0076x over previous
//
#include <hip/hip_runtime.h>

// ---------------------------------------------------------------------------
// BiLSTM + CRF on MI355X — R9: scan = 128KB LDS weight slab (K-half for all
// 64 col-tiles) + per-step fresh streamed loads for the other K-half.
// R5-R8 forensics: RA VGPR budget ~56-128 is immovable; pinned weights get
// scratch-spilled (same TA cost as streaming). R8 showed byte count matters
// less than TA-issue/latency: 16 waves > 8. So: half the weight bytes leave
// the TA path entirely (LDS slab, separate pipe), the rest are fresh
// per-step loads issued early (schedulable, unspillable).
// ---------------------------------------------------------------------------

typedef short v8s __attribute__((ext_vector_type(8)));
typedef float v4f __attribute__((ext_vector_type(4)));
typedef int   i4v __attribute__((ext_vector_type(4)));
typedef float v2f __attribute__((ext_vector_type(2)));

__device__ __forceinline__ short f2b(float f){
  unsigned u = __float_as_uint(f);
  u = u + 0x7fffu + ((u >> 16) & 1u);          // RNE
  return (short)(u >> 16);
}
__device__ __forceinline__ float b2f(short s){
  return __uint_as_float(((unsigned)(unsigned short)s) << 16);
}
__device__ __forceinline__ float sigm(float x){ return 1.f/(1.f+__expf(-x)); }
__device__ __forceinline__ float tanh_(float x){ return 1.f - 2.f/(__expf(2.f*x)+1.f); }
__device__ __forceinline__ float sel4(short4 v, int rr){
  return b2f(rr==0 ? v.x : rr==1 ? v.y : rr==2 ? v.z : v.w);
}

// ---------------------------------------------------------------------------
// prep (unchanged from R8)
// ---------------------------------------------------------------------------
__global__ void prep_kernel(const float* wihf, const float* whhf,
                            const float* wihb, const float* whhb,
                            const float* bihf, const float* bhhf,
                            const float* bihb, const float* bhhb,
                            short* wswz, unsigned char* whh8,
                            float* cb, float* em, float* outp)
{
  int gid = blockIdx.x * 256 + threadIdx.x;      // 131072 threads
  if(gid < 65536){
    int mat = gid >> 15;                 // 0 = fwd, 1 = bwd
    int rem = gid & 32767;
    int ct = rem >> 9;
    int kk = (rem >> 6) & 7;
    int lane = rem & 63;
    const float* src = mat ? wihb : wihf;
    int g  = ct*16 + (lane & 15);
    int k0 = kk*32 + (lane >> 4)*8;
    v8s o;
#pragma unroll
    for(int j=0;j<8;j++) o[j] = f2b(src[g*256 + k0 + j]);
    *(v8s*)(wswz + ((long)mat << 18) + ((long)((ct*8+kk)*64 + lane) << 3)) = o;
  } else if(gid < 98304){
    int j2 = gid - 65536;
    int dir = j2 >> 14;
    int rem = j2 & 16383;
    int ct = rem >> 8;
    int kp = (rem >> 6) & 3;
    int lane = rem & 63;
    int lm = lane & 15, lq = lane >> 4;
    const float* src = dir ? whhb : whhf;
    int g = ct*16 + lm;
    i4v ov;
    {
      const float* s = src + g*256 + (2*kp)*32 + lq*8;
      int a0 = __builtin_amdgcn_cvt_pk_fp8_f32(s[0], s[1], 0, 0);
      a0 = __builtin_amdgcn_cvt_pk_fp8_f32(s[2], s[3], a0, 1);
      int a1 = __builtin_amdgcn_cvt_pk_fp8_f32(s[4], s[5], 0, 0);
      a1 = __builtin_amdgcn_cvt_pk_fp8_f32(s[6], s[7], a1, 1);
      ov[0] = a0; ov[1] = a1;
    }
    {
      const float* s = src + g*256 + (2*kp+1)*32 + lq*8;
      int a0 = __builtin_amdgcn_cvt_pk_fp8_f32(s[0], s[1], 0, 0);
      a0 = __builtin_amdgcn_cvt_pk_fp8_f32(s[2], s[3], a0, 1);
      int a1 = __builtin_amdgcn_cvt_pk_fp8_f32(s[4], s[5], 0, 0);
      a1 = __builtin_amdgcn_cvt_pk_fp8_f32(s[6], s[7], a1, 1);
      ov[2] = a0; ov[3] = a1;
    }
    *(i4v*)(whh8 + (long)dir*262144 + ((ct*4+kp)<<10) + lane*16) = ov;
  } else if(gid < 100352){
    int j3 = gid - 98304;
    int dir = j3 >> 10, gg = j3 & 1023;
    cb[j3] = dir ? (bihb[gg] + bhhb[gg]) : (bihf[gg] + bhhf[gg]);
  }
  for(int i=gid; i<589824; i+=131072) em[i] = 0.f;
  if(gid == 0) *outp = 0.f;
}

// ---------------------------------------------------------------------------
// xg_gemm (unchanged from R8)
// ---------------------------------------------------------------------------
__global__ __launch_bounds__(256,2) void xg_gemm(const int* X, const float* emb,
     const short* wswz, const float* cb, short* xg, int t_base, int CT)
{
  int dir = blockIdx.x & 1;
  int tl  = blockIdx.x >> 1;
  int rh  = blockIdx.y;
  int tg  = t_base + tl;
  int tt  = dir ? (511 - tg) : tg;
  __shared__ short a_sh[64*264];
  int tid = threadIdx.x;
  {
    int row = tid >> 2, seg = tid & 3;
    int b = rh*64 + row;
    int idx = X[b*512 + tt];
    const float* erow = emb + (long)idx*256 + seg*64;
    short* dst = a_sh + row*264 + seg*64;
#pragma unroll
    for(int c=0;c<8;c++){
      float4 f0 = ((const float4*)erow)[2*c];
      float4 f1 = ((const float4*)erow)[2*c+1];
      v8s p;
      p[0]=f2b(f0.x); p[1]=f2b(f0.y); p[2]=f2b(f0.z); p[3]=f2b(f0.w);
      p[4]=f2b(f1.x); p[5]=f2b(f1.y); p[6]=f2b(f1.z); p[7]=f2b(f1.w);
      *(v8s*)(dst + c*8) = p;
    }
  }
  __syncthreads();
  int w = tid >> 6, lane = tid & 63, lm = lane & 15, lq = lane >> 4;
  v8s A[4][8];
#pragma unroll
  for(int mt=0;mt<4;mt++)
#pragma unroll
    for(int kk=0;kk<8;kk++)
      A[mt][kk] = *(const v8s*)(a_sh + (mt*16+lm)*264 + kk*32 + lq*8);

  const short* wmat = wswz + ((long)dir << 18);
  const float* cbd  = cb + dir*1024;
  short* xgd = xg + ((long)dir*CT + tl)*131072;

  v8s Bb[2][8];
  {
    const short* bp = wmat + (long)(w*16)*4096 + lane*8;
#pragma unroll
    for(int kk=0;kk<8;kk++) Bb[0][kk] = *(const v8s*)(bp + kk*512);
  }
#pragma unroll
  for(int ci=0;ci<16;ci++){
    int cur = ci & 1;
    int ct = w*16 + ci;
    if(ci < 15){
      const short* bp = wmat + (long)(ct+1)*4096 + lane*8;
#pragma unroll
      for(int kk=0;kk<8;kk++) Bb[cur^1][kk] = *(const v8s*)(bp + kk*512);
    }
    float bias = cbd[ct*16 + lm];
    v4f acc[4];
#pragma unroll
    for(int mt=0;mt<4;mt++) acc[mt] = (v4f){bias,bias,bias,bias};
#pragma unroll
    for(int kk=0;kk<8;kk++)
#pragma unroll
      for(int mt=0;mt<4;mt++)
        acc[mt] = __builtin_amdgcn_mfma_f32_16x16x32_bf16(A[mt][kk], Bb[cur][kk], acc[mt], 0,0,0);
#pragma unroll
    for(int mt=0;mt<4;mt++){
      int r = rh*4 + mt;
      long off = (long)r*16384 + ct*256 + lane*4;
      short4 s4;
      s4.x = f2b(acc[mt][0]); s4.y = f2b(acc[mt][1]);
      s4.z = f2b(acc[mt][2]); s4.w = f2b(acc[mt][3]);
      *(short4*)(xgd + off) = s4;
    }
  }
}

// ---------------------------------------------------------------------------
// lstm_scan_s<SK>: 16 wgs (dir x rowgroup of 16 rows), 1024 thr = 16 waves.
// Wave w owns col-tiles ct = {grp*16 + w}. Weight K-blocks kp<SK live in a
// persistent LDS slab (SK*64KB, filled once); kp>=SK are streamed fresh from
// whh8 (L2-hot) each step, issued at step top, consumed in the last MFMAs.
// h fp8 in LDS dbuf; one barrier/step; state carried via global buffers.
// Dyn LDS: SK*65536 (slab) + 8704 (h dbuf).
// ---------------------------------------------------------------------------
template<int SK>
__global__ __launch_bounds__(1024) void lstm_scan_s(
     const short* __restrict__ xg,
     const unsigned char* __restrict__ whh8,
     unsigned char* __restrict__ hg8,
     float* __restrict__ c_state,
     unsigned char* __restrict__ h_state,
     int first, int CT)
{
  extern __shared__ unsigned char lds[];
  unsigned char* hbuf = lds + SK*65536;
  int wg = blockIdx.x;           // 16
  int dir = wg >> 3, r = wg & 7;
  int tid = threadIdx.x, w = tid >> 6, lane = tid & 63, lm = lane & 15, lq = lane >> 4;
  const unsigned char* __restrict__ whhd = whh8 + (long)dir*262144;
  const unsigned char* slab_w = lds + (w*4*SK)*1024;

  // fill persistent slab: chunk layout (w, grp, kp<SK), 1KB each
  if(SK > 0){
#pragma unroll 1
    for(int ofs = tid*16; ofs < SK*65536; ofs += 16384){
      int chunk = ofs >> 10;
      int inner = ofs & 1023;
      int w2  = chunk / (4*SK);
      int rem = chunk - w2*(4*SK);
      int grp = rem / SK;
      int kp  = rem - grp*SK;
      int ct = grp*16 + w2;
      *(i4v*)(lds + ofs) = *(const i4v*)(whhd + ((ct*4+kp)<<10) + inner);
    }
  }

  float c[4];
  if(first){
    for(int i=tid; i<8704; i+=1024) hbuf[i] = 0;
#pragma unroll
    for(int i=0;i<4;i++) c[i] = 0.f;
  } else {
    int row = tid >> 6, col = tid & 63;
    *(int*)(hbuf + row*272 + col*4) = *(const int*)(h_state + wg*4096 + row*256 + col*4);
#pragma unroll
    for(int i=0;i<4;i++) c[i] = c_state[(wg*1024 + tid)*4 + i];
  }
  __syncthreads();

  int p = 0;
  for(int tl=0; tl<CT; tl++){
    // streamed K-half: fresh loads each step, issued up front (L2-hot)
    i4v Bs[4*(4-SK)];
#pragma unroll
    for(int grp=0; grp<4; grp++)
#pragma unroll
      for(int kp=SK; kp<4; kp++){
        int ct = grp*16 + w;
        Bs[grp*(4-SK) + (kp-SK)] = *(const i4v*)(whhd + ((ct*4+kp)<<10) + lane*16);
      }

    const short* __restrict__ xgt = xg + ((long)dir*CT + tl)*131072 + (long)r*16384 + lane*4;
    short4 xv[4];
#pragma unroll
    for(int grp=0;grp<4;grp++)
      xv[grp] = *(const short4*)(xgt + (grp*16 + w)*256);

    const unsigned char* hb = hbuf + p*4352;
    long A[8];
#pragma unroll
    for(int kk=0;kk<8;kk++)
      A[kk] = *(const long*)(hb + lm*272 + kk*32 + lq*8);

    v4f acc[4];
#pragma unroll
    for(int grp=0;grp<4;grp++) acc[grp] = (v4f){0.f,0.f,0.f,0.f};

#pragma unroll
    for(int grp=0;grp<4;grp++){
      i4v Bl[SK > 0 ? SK : 1];
      if(SK > 0){
#pragma unroll
        for(int kp=0; kp<SK; kp++)
          Bl[kp] = *(const i4v*)(slab_w + (grp*SK+kp)*1024 + lane*16);
      }
#pragma unroll
      for(int kk=0;kk<8;kk++){
        int kp = kk >> 1;
        union { i4v v; long l[2]; } u;
        u.v = (kp < SK) ? Bl[kp < SK ? kp : 0] : Bs[grp*(4-SK) + (kp-SK >= 0 ? kp-SK : 0)];
        acc[grp] = __builtin_amdgcn_mfma_f32_16x16x32_fp8_fp8(A[kk], u.l[kk&1], acc[grp], 0,0,0);
      }
    }

    unsigned char* hnew = hbuf + (p^1)*4352;
    {
      int d = 16*w + lm;
      float hv[4];
#pragma unroll
      for(int rr=0;rr<4;rr++){
        float ig = acc[0][rr] + sel4(xv[0], rr);
        float fg = acc[1][rr] + sel4(xv[1], rr);
        float gg = acc[2][rr] + sel4(xv[2], rr);
        float og = acc[3][rr] + sel4(xv[3], rr);
        float cn = sigm(fg)*c[rr] + sigm(ig)*tanh_(gg);
        c[rr] = cn;
        hv[rr] = sigm(og)*tanh_(cn);
      }
      int packed = __builtin_amdgcn_cvt_pk_fp8_f32(hv[0], hv[1], 0, 0);
      packed = __builtin_amdgcn_cvt_pk_fp8_f32(hv[2], hv[3], packed, 1);
#pragma unroll
      for(int rr=0;rr<4;rr++)
        hnew[(lq*4+rr)*272 + d] = (unsigned char)((packed >> (8*rr)) & 0xff);
    }
    __syncthreads();
    {
      int row = tid >> 6, col = tid & 63;
      *(int*)(hg8 + ((long)dir*CT + tl)*32768 + (r*16+row)*256 + col*4)
        = *(const int*)(hnew + row*272 + col*4);
    }
    p ^= 1;
  }
  // persist state for next chunk
  {
    int row = tid >> 6, col = tid & 63;
    const unsigned char* hb = hbuf + p*4352;
    *(int*)(h_state + wg*4096 + row*256 + col*4) = *(const int*)(hb + row*272 + col*4);
#pragma unroll
    for(int i=0;i<4;i++) c_state[(wg*1024 + tid)*4 + i] = c[i];
  }
}

// ---------------------------------------------------------------------------
// emiss_partial (unchanged)
// ---------------------------------------------------------------------------
__global__ void emiss_partial(const unsigned char* hg8, const float* lin_w,
                              float* em, int t_base, int CT)
{
  int dir = blockIdx.y;
  int wv  = blockIdx.x*4 + (threadIdx.x >> 6);
  int lane = threadIdx.x & 63;
  int tl = wv >> 7, b = wv & 127;
  int s = dir ? (511 - (t_base + tl)) : (t_base + tl);
  int v = *(const int*)(hg8 + ((long)dir*CT + tl)*32768 + b*256 + lane*4);
  v2f lo = __builtin_amdgcn_cvt_pk_f32_fp8(v, 0);
  v2f hi = __builtin_amdgcn_cvt_pk_f32_fp8(v, 1);
  float x0 = lo[0], x1 = lo[1], x2 = hi[0], x3 = hi[1];
  const float* wbase = lin_w + dir*256 + lane*4;
  float part[9];
#pragma unroll
  for(int j=0;j<9;j++){
    float4 wf = *(const float4*)(wbase + j*512);
    part[j] = x0*wf.x + x1*wf.y + x2*wf.z + x3*wf.w;
  }
#pragma unroll
  for(int j=0;j<9;j++){
    float vv = part[j];
#pragma unroll
    for(int off=32; off>0; off>>=1) vv += __shfl_down(vv, off);
    if(lane == 0) em[((long)b*512 + s)*9 + j] += vv;
  }
}

// ---------------------------------------------------------------------------
// CRF (unchanged)
// ---------------------------------------------------------------------------
__global__ void crf_kernel(const float* em, const int* y, const unsigned char* maskb,
                           const float* st, const float* en, const float* tr,
                           const float* lin_b, float* out)
{
  int b = blockIdx.x;
  int lane = threadIdx.x;
  bool isb = (maskb[1] != 0);
  int len = 0;
  for(int k=lane; k<512; k+=64){
    unsigned char mv = isb ? maskb[b*512 + k] : maskb[((long)(b*512 + k))*4];
    len += (mv != 0);
  }
#pragma unroll
  for(int off=32; off>0; off>>=1) len += __shfl_xor(len, off);

  const int* yb = y + b*512;
  float np = 0.f;
  for(int t=lane; t<512; t+=64){
    if(t >= 1 && t < len){
      int yp = yb[t-1], yt = yb[t];
      np += tr[yp*9 + yt] + em[((long)b*512 + t)*9 + yt] + lin_b[yt];
    }
  }
#pragma unroll
  for(int off=32; off>0; off>>=1) np += __shfl_xor(np, off);

  int j = lane;
  float alpha = -1e30f;
  float trc[9];
  float lb = (j < 9) ? lin_b[j] : 0.f;
  if(j < 9){
    alpha = st[j] + em[(long)b*512*9 + j] + lb;
#pragma unroll
    for(int i=0;i<9;i++) trc[i] = tr[i*9 + j];
  }
  for(int t=1; t<len; t++){
    float av[9];
#pragma unroll
    for(int i=0;i<9;i++) av[i] = __shfl(alpha, i);
    if(j < 9){
      float m = av[0] + trc[0];
#pragma unroll
      for(int i=1;i<9;i++) m = fmaxf(m, av[i] + trc[i]);
      float ssum = 0.f;
#pragma unroll
      for(int i=0;i<9;i++) ssum += __expf(av[i] + trc[i] - m);
      alpha = m + __logf(ssum) + em[((long)b*512 + t)*9 + j] + lb;
    }
  }
  float aj = (j < 9) ? (alpha + en[j]) : -1e30f;
  float mm = aj;
#pragma unroll
  for(int off=32; off>0; off>>=1) mm = fmaxf(mm, __shfl_xor(mm, off));
  float ee = (j < 9) ? __expf(aj - mm) : 0.f;
#pragma unroll
  for(int off=32; off>0; off>>=1) ee += __shfl_xor(ee, off);
  float den = mm + __logf(ee);
  if(lane == 0){
    int y0 = yb[0];
    float num = np + st[y0] + em[(long)b*512*9 + y0] + lin_b[y0] + en[yb[len-1]];
    atomicAdd(out, num - den);
  }
}

// ---------------------------------------------------------------------------
extern "C" void kernel_launch(void* const* d_in, const int* in_sizes, int n_in,
                              void* d_out, int out_size, void* d_ws, size_t ws_size,
                              hipStream_t stream)
{
  (void)in_sizes; (void)n_in; (void)out_size;
  const int*   X    = (const int*)d_in[0];
  const int*   y    = (const int*)d_in[1];
  const unsigned char* maskb = (const unsigned char*)d_in[2];
  const float* emb  = (const float*)d_in[3];
  const float* wihf = (const float*)d_in[4];
  const float* whhf = (const float*)d_in[5];
  const float* bihf = (const float*)d_in[6];
  const float* bhhf = (const float*)d_in[7];
  const float* wihb = (const float*)d_in[8];
  const float* whhb = (const float*)d_in[9];
  const float* bihb = (const float*)d_in[10];
  const float* bhhb = (const float*)d_in[11];
  const float* lin_w= (const float*)d_in[12];
  const float* lin_b= (const float*)d_in[13];
  const float* st   = (const float*)d_in[14];
  const float* en   = (const float*)d_in[15];
  const float* tr   = (const float*)d_in[16];

  // ws layout (bytes)
  const long FIXED = 4268032L;
  long CT = 256;
  while (CT > 16 && FIXED + CT*589824L > (long)ws_size) CT >>= 1;
  int NC = (int)(512 / CT);

  char* ws = (char*)d_ws;
  short*         wswz = (short*)(ws);                  // 1,048,576 B (bf16 w_ih frags)
  unsigned char* whh8 = (unsigned char*)(ws + 1048576L); //   524,288 B (fp8 w_hh frags)
  float*         cb   = (float*)(ws + 1572864L);       //     8,192 B
  float*         cst  = (float*)(ws + 1581056L);       //   262,144 B
  unsigned char* hst  = (unsigned char*)(ws + 1843200L); //    65,536 B
  float*         em   = (float*)(ws + 1908736L);       // 2,359,296 B
  short*         xg   = (short*)(ws + 4268032L);       // CT*524,288 B
  unsigned char* hg8  = (unsigned char*)(ws + 4268032L + CT*524288L); // CT*65,536 B

  const int LDS_S2 = 2*65536 + 8704;   // 139,776 B (proven allocatable in R3)
  bool big = (hipFuncSetAttribute(reinterpret_cast<const void*>(&lstm_scan_s<2>),
              hipFuncAttributeMaxDynamicSharedMemorySize, LDS_S2) == hipSuccess);

  prep_kernel<<<512, 256, 0, stream>>>(wihf, whhf, wihb, whhb,
                                       bihf, bhhf, bihb, bhhb,
                                       wswz, whh8, cb, em, (float*)d_out);
  for(int ck=0; ck<NC; ck++){
    int tb = ck*(int)CT;
    xg_gemm<<<dim3(2*(int)CT, 2), 256, 0, stream>>>(X, emb, wswz, cb, xg, tb, (int)CT);
    if(big)
      lstm_scan_s<2><<<16, 1024, LDS_S2, stream>>>(xg, whh8, hg8, cst, hst, ck==0 ? 1 : 0, (int)CT);
    else
      lstm_scan_s<0><<<16, 1024, 8704, stream>>>(xg, whh8, hg8, cst, hst, ck==0 ? 1 : 0, (int)CT);
    emiss_partial<<<dim3(32*(int)CT, 2), 256, 0, stream>>>(hg8, lin_w, em, tb, (int)CT);
  }
  crf_kernel<<<128, 64, 0, stream>>>(em, y, maskb, st, en, tr, lin_b, (float*)d_out);
}

// Round 10
// 1982.592 us; speedup vs baseline: 1.2739x; 1.1104x over previous
//
#include <hip/hip_runtime.h>

// ---------------------------------------------------------------------------
// BiLSTM + CRF on MI355X — R10: MX-FP4 w_hh, whole weight matrix in LDS.
// R5-R9 forensics: fp8 w_hh (256KB/dir) can't be made resident (LDS 160KB,
// RA budget ~56-128 VGPRs immovable) and halving the stream twice was flat
// -> scan is step-latency bound on the per-step barrier + global drain.
// Fix: w_hh -> MXFP4 (e2m1 + per-32 e8m0 scales) = 128KB/dir -> full LDS
// slab; gates via mfma_scale_f32_16x16x128_f8f6f4 (A=h fp8 cbsz=0,
// B=fp4 blgp=4). Per-step global traffic: xv 32KB + hg8 4KB only.
// Fallback (if >64KB dyn LDS refused): R9 streaming-fp8 scan.
// ---------------------------------------------------------------------------

typedef short v8s __attribute__((ext_vector_type(8)));
typedef float v4f __attribute__((ext_vector_type(4)));
typedef int   i4v __attribute__((ext_vector_type(4)));
typedef int   i8v __attribute__((ext_vector_type(8)));
typedef float v2f __attribute__((ext_vector_type(2)));

__device__ __forceinline__ short f2b(float f){
  unsigned u = __float_as_uint(f);
  u = u + 0x7fffu + ((u >> 16) & 1u);          // RNE
  return (short)(u >> 16);
}
__device__ __forceinline__ float b2f(short s){
  return __uint_as_float(((unsigned)(unsigned short)s) << 16);
}
__device__ __forceinline__ float sigm(float x){ return 1.f/(1.f+__expf(-x)); }
__device__ __forceinline__ float tanh_(float x){ return 1.f - 2.f/(__expf(2.f*x)+1.f); }
__device__ __forceinline__ float sel4(short4 v, int rr){
  return b2f(rr==0 ? v.x : rr==1 ? v.y : rr==2 ? v.z : v.w);
}
// e2m1 nearest: mags {0,.5,1,1.5,2,3,4,6}, code = sign<<3 | mag-index
__device__ __forceinline__ int fp4q(float v){
  int s = (v < 0.f) ? 8 : 0;
  float av = fabsf(v);
  int m;
  if(av < 0.25f) m=0; else if(av < 0.75f) m=1; else if(av < 1.25f) m=2;
  else if(av < 1.75f) m=3; else if(av < 2.5f) m=4; else if(av < 3.5f) m=5;
  else if(av < 5.f) m=6; else m=7;
  return s | m;
}

// ---------------------------------------------------------------------------
// prep:
//  gid <  65536          : w_ih_{f,b} -> bf16 B-frag swizzle (wswz)
//  65536  <= gid < 73728 : w_hh -> MXFP4 frags (whh4) + e8m0 scales (whsc)
//  73728  <= gid < 106496: w_hh -> fp8 frags (whh8)  [fallback path only]
//  106496 <= gid < 108544: cb = b_ih + b_hh
//  all                   : zero em; gid 0 zeros out.
// ---------------------------------------------------------------------------
__global__ void prep_kernel(const float* wihf, const float* whhf,
                            const float* wihb, const float* whhb,
                            const float* bihf, const float* bhhf,
                            const float* bihb, const float* bhhb,
                            short* wswz, unsigned char* whh4, int2* whsc,
                            unsigned char* whh8, float* cb, float* em, float* outp)
{
  int gid = blockIdx.x * 256 + threadIdx.x;      // 131072 threads
  if(gid < 65536){
    int mat = gid >> 15;                 // 0 = fwd, 1 = bwd
    int rem = gid & 32767;
    int ct = rem >> 9;
    int kk = (rem >> 6) & 7;
    int lane = rem & 63;
    const float* src = mat ? wihb : wihf;
    int g  = ct*16 + (lane & 15);
    int k0 = kk*32 + (lane >> 4)*8;
    v8s o;
#pragma unroll
    for(int j=0;j<8;j++) o[j] = f2b(src[g*256 + k0 + j]);
    *(v8s*)(wswz + ((long)mat << 18) + ((long)((ct*8+kk)*64 + lane) << 3)) = o;
  } else if(gid < 73728){
    // MXFP4: thread per (dir, ct, lane), both K-halves of 128
    int j2 = gid - 65536;                // 8192
    int dir = j2 >> 12;
    int rem = j2 & 4095;
    int ct = rem >> 6;
    int lane = rem & 63;
    const float* src = dir ? whhb : whhf;
    int g = ct*16 + (lane & 15);
    int sc0 = 127, sc1 = 127;
#pragma unroll
    for(int half=0; half<2; half++){
      const float* s = src + g*256 + half*128 + (lane>>4)*32;
      float am = 0.f;
#pragma unroll
      for(int j=0;j<32;j++) am = fmaxf(am, fabsf(s[j]));
      int e = 0;
      if(am > 0.f){
        e = (int)ceilf(log2f(am * (1.f/6.f)));
        e = e < -126 ? -126 : (e > 127 ? 127 : e);
      }
      float inv = exp2f((float)(-e));
      i4v ov;
#pragma unroll
      for(int wi=0; wi<4; wi++){
        int word = 0;
#pragma unroll
        for(int bj=0; bj<4; bj++){
          int j0 = (wi*4 + bj)*2;        // low nibble = lower k
          int c0 = fp4q(s[j0]*inv), c1 = fp4q(s[j0+1]*inv);
          word |= (c0 | (c1<<4)) << (8*bj);
        }
        ov[wi] = word;
      }
      *(i4v*)(whh4 + ((long)((dir*64+ct)*2 + half) << 10) + lane*16) = ov;
      if(half == 0) sc0 = e + 127; else sc1 = e + 127;
    }
    whsc[(dir*64+ct)*64 + lane] = make_int2(sc0, sc1);
  } else if(gid < 106496){
    int j2 = gid - 73728;
    int dir = j2 >> 14;
    int rem = j2 & 16383;
    int ct = rem >> 8;
    int kp = (rem >> 6) & 3;
    int lane = rem & 63;
    int lm = lane & 15, lq = lane >> 4;
    const float* src = dir ? whhb : whhf;
    int g = ct*16 + lm;
    i4v ov;
    {
      const float* s = src + g*256 + (2*kp)*32 + lq*8;
      int a0 = __builtin_amdgcn_cvt_pk_fp8_f32(s[0], s[1], 0, 0);
      a0 = __builtin_amdgcn_cvt_pk_fp8_f32(s[2], s[3], a0, 1);
      int a1 = __builtin_amdgcn_cvt_pk_fp8_f32(s[4], s[5], 0, 0);
      a1 = __builtin_amdgcn_cvt_pk_fp8_f32(s[6], s[7], a1, 1);
      ov[0] = a0; ov[1] = a1;
    }
    {
      const float* s = src + g*256 + (2*kp+1)*32 + lq*8;
      int a0 = __builtin_amdgcn_cvt_pk_fp8_f32(s[0], s[1], 0, 0);
      a0 = __builtin_amdgcn_cvt_pk_fp8_f32(s[2], s[3], a0, 1);
      int a1 = __builtin_amdgcn_cvt_pk_fp8_f32(s[4], s[5], 0, 0);
      a1 = __builtin_amdgcn_cvt_pk_fp8_f32(s[6], s[7], a1, 1);
      ov[2] = a0; ov[3] = a1;
    }
    *(i4v*)(whh8 + (long)dir*262144 + ((ct*4+kp)<<10) + lane*16) = ov;
  } else if(gid < 108544){
    int j3 = gid - 106496;
    int dir = j3 >> 10, gg = j3 & 1023;
    cb[j3] = dir ? (bihb[gg] + bhhb[gg]) : (bihf[gg] + bhhf[gg]);
  }
  for(int i=gid; i<589824; i+=131072) em[i] = 0.f;
  if(gid == 0) *outp = 0.f;
}

// ---------------------------------------------------------------------------
// xg_gemm (unchanged from R9)
// ---------------------------------------------------------------------------
__global__ __launch_bounds__(256,2) void xg_gemm(const int* X, const float* emb,
     const short* wswz, const float* cb, short* xg, int t_base, int CT)
{
  int dir = blockIdx.x & 1;
  int tl  = blockIdx.x >> 1;
  int rh  = blockIdx.y;
  int tg  = t_base + tl;
  int tt  = dir ? (511 - tg) : tg;
  __shared__ short a_sh[64*264];
  int tid = threadIdx.x;
  {
    int row = tid >> 2, seg = tid & 3;
    int b = rh*64 + row;
    int idx = X[b*512 + tt];
    const float* erow = emb + (long)idx*256 + seg*64;
    short* dst = a_sh + row*264 + seg*64;
#pragma unroll
    for(int c=0;c<8;c++){
      float4 f0 = ((const float4*)erow)[2*c];
      float4 f1 = ((const float4*)erow)[2*c+1];
      v8s p;
      p[0]=f2b(f0.x); p[1]=f2b(f0.y); p[2]=f2b(f0.z); p[3]=f2b(f0.w);
      p[4]=f2b(f1.x); p[5]=f2b(f1.y); p[6]=f2b(f1.z); p[7]=f2b(f1.w);
      *(v8s*)(dst + c*8) = p;
    }
  }
  __syncthreads();
  int w = tid >> 6, lane = tid & 63, lm = lane & 15, lq = lane >> 4;
  v8s A[4][8];
#pragma unroll
  for(int mt=0;mt<4;mt++)
#pragma unroll
    for(int kk=0;kk<8;kk++)
      A[mt][kk] = *(const v8s*)(a_sh + (mt*16+lm)*264 + kk*32 + lq*8);

  const short* wmat = wswz + ((long)dir << 18);
  const float* cbd  = cb + dir*1024;
  short* xgd = xg + ((long)dir*CT + tl)*131072;

  v8s Bb[2][8];
  {
    const short* bp = wmat + (long)(w*16)*4096 + lane*8;
#pragma unroll
    for(int kk=0;kk<8;kk++) Bb[0][kk] = *(const v8s*)(bp + kk*512);
  }
#pragma unroll
  for(int ci=0;ci<16;ci++){
    int cur = ci & 1;
    int ct = w*16 + ci;
    if(ci < 15){
      const short* bp = wmat + (long)(ct+1)*4096 + lane*8;
#pragma unroll
      for(int kk=0;kk<8;kk++) Bb[cur^1][kk] = *(const v8s*)(bp + kk*512);
    }
    float bias = cbd[ct*16 + lm];
    v4f acc[4];
#pragma unroll
    for(int mt=0;mt<4;mt++) acc[mt] = (v4f){bias,bias,bias,bias};
#pragma unroll
    for(int kk=0;kk<8;kk++)
#pragma unroll
      for(int mt=0;mt<4;mt++)
        acc[mt] = __builtin_amdgcn_mfma_f32_16x16x32_bf16(A[mt][kk], Bb[cur][kk], acc[mt], 0,0,0);
#pragma unroll
    for(int mt=0;mt<4;mt++){
      int r = rh*4 + mt;
      long off = (long)r*16384 + ct*256 + lane*4;
      short4 s4;
      s4.x = f2b(acc[mt][0]); s4.y = f2b(acc[mt][1]);
      s4.z = f2b(acc[mt][2]); s4.w = f2b(acc[mt][3]);
      *(short4*)(xgd + off) = s4;
    }
  }
}

// ---------------------------------------------------------------------------
// lstm_scan4: 16 wgs (dir x rowgroup of 16 rows), 1024 thr = 16 waves.
// Full dir w_hh (MXFP4, 128KB) in LDS slab; scales in 8 regs/wave; A = h fp8
// K=128 frags from LDS dbuf; 8 mfma_scale per wave per step; zero per-step
// weight traffic. Dyn LDS = 131072 + 8704 = 139,776 B.
// ---------------------------------------------------------------------------
__global__ __launch_bounds__(1024,1) void lstm_scan4(
     const short* __restrict__ xg,
     const unsigned char* __restrict__ whh4,
     const int2* __restrict__ whsc,
     unsigned char* __restrict__ hg8,
     float* __restrict__ c_state,
     unsigned char* __restrict__ h_state,
     int first, int CT)
{
  extern __shared__ unsigned char lds[];
  unsigned char* hbuf = lds + 131072;
  int wg = blockIdx.x;           // 16
  int dir = wg >> 3, r = wg & 7;
  int tid = threadIdx.x, w = tid >> 6, lane = tid & 63, lm = lane & 15, lq = lane >> 4;

  // fill slab: layout identical to whh4 (linear copy of this dir's 128KB)
  {
    const unsigned char* w4d = whh4 + (long)dir*131072;
#pragma unroll
    for(int ofs = tid*16; ofs < 131072; ofs += 16384)
      *(i4v*)(lds + ofs) = *(const i4v*)(w4d + ofs);
  }
  // per-wave block scales (e8m0 bytes), 2 per owned col-tile
  int scb[4][2];
#pragma unroll
  for(int grp=0; grp<4; grp++){
    int2 s2 = whsc[(dir*64 + grp*16 + w)*64 + lane];
    scb[grp][0] = s2.x; scb[grp][1] = s2.y;
  }

  float c[4];
  if(first){
    for(int i=tid; i<8704; i+=1024) hbuf[i] = 0;
#pragma unroll
    for(int i=0;i<4;i++) c[i] = 0.f;
  } else {
    int row = tid >> 6, col = tid & 63;
    *(int*)(hbuf + row*272 + col*4) = *(const int*)(h_state + wg*4096 + row*256 + col*4);
#pragma unroll
    for(int i=0;i<4;i++) c[i] = c_state[(wg*1024 + tid)*4 + i];
  }
  __syncthreads();

  int p = 0;
  for(int tl=0; tl<CT; tl++){
    const short* __restrict__ xgt = xg + ((long)dir*CT + tl)*131072 + (long)r*16384 + lane*4;
    short4 xv[4];
#pragma unroll
    for(int grp=0;grp<4;grp++)
      xv[grp] = *(const short4*)(xgt + (grp*16 + w)*256);

    const unsigned char* hb = hbuf + p*4352;
    // A frags: h fp8, K=128 per half; lane(m=lm, kblock=lq) holds 32B
    i8v A8[2];
#pragma unroll
    for(int half=0; half<2; half++){
      i4v a0 = *(const i4v*)(hb + lm*272 + half*128 + lq*32);
      i4v a1 = *(const i4v*)(hb + lm*272 + half*128 + lq*32 + 16);
      i8v t;
#pragma unroll
      for(int j=0;j<4;j++){ t[j] = a0[j]; t[4+j] = a1[j]; }
      A8[half] = t;
    }

    v4f acc[4];
#pragma unroll
    for(int grp=0;grp<4;grp++) acc[grp] = (v4f){0.f,0.f,0.f,0.f};

#pragma unroll
    for(int grp=0;grp<4;grp++){
      long base = (long)((grp*16 + w)*2) << 10;
      i4v b0 = *(const i4v*)(lds + base + lane*16);
      i4v b1 = *(const i4v*)(lds + base + 1024 + lane*16);
      i8v B0, B1;
#pragma unroll
      for(int j=0;j<4;j++){ B0[j] = b0[j]; B0[4+j] = 0; B1[j] = b1[j]; B1[4+j] = 0; }
      // A fp8 (cbsz=0) scale 1.0 (127); B fp4 (blgp=4) per-block scale
      acc[grp] = __builtin_amdgcn_mfma_scale_f32_16x16x128_f8f6f4(
                   A8[0], B0, acc[grp], 0, 4, 0, 127, 0, scb[grp][0]);
      acc[grp] = __builtin_amdgcn_mfma_scale_f32_16x16x128_f8f6f4(
                   A8[1], B1, acc[grp], 0, 4, 0, 127, 0, scb[grp][1]);
    }

    unsigned char* hnew = hbuf + (p^1)*4352;
    {
      int d = 16*w + lm;
      float hv[4];
#pragma unroll
      for(int rr=0;rr<4;rr++){
        float ig = acc[0][rr] + sel4(xv[0], rr);
        float fg = acc[1][rr] + sel4(xv[1], rr);
        float gg = acc[2][rr] + sel4(xv[2], rr);
        float og = acc[3][rr] + sel4(xv[3], rr);
        float cn = sigm(fg)*c[rr] + sigm(ig)*tanh_(gg);
        c[rr] = cn;
        hv[rr] = sigm(og)*tanh_(cn);
      }
      int packed = __builtin_amdgcn_cvt_pk_fp8_f32(hv[0], hv[1], 0, 0);
      packed = __builtin_amdgcn_cvt_pk_fp8_f32(hv[2], hv[3], packed, 1);
#pragma unroll
      for(int rr=0;rr<4;rr++)
        hnew[(lq*4+rr)*272 + d] = (unsigned char)((packed >> (8*rr)) & 0xff);
    }
    __syncthreads();
    {
      int row = tid >> 6, col = tid & 63;
      *(int*)(hg8 + ((long)dir*CT + tl)*32768 + (r*16+row)*256 + col*4)
        = *(const int*)(hnew + row*272 + col*4);
    }
    p ^= 1;
  }
  {
    int row = tid >> 6, col = tid & 63;
    const unsigned char* hb = hbuf + p*4352;
    *(int*)(h_state + wg*4096 + row*256 + col*4) = *(const int*)(hb + row*272 + col*4);
#pragma unroll
    for(int i=0;i<4;i++) c_state[(wg*1024 + tid)*4 + i] = c[i];
  }
}

// ---------------------------------------------------------------------------
// lstm_scan_s0: R9's pure-streaming fp8 scan (fallback if big LDS refused)
// ---------------------------------------------------------------------------
__global__ __launch_bounds__(1024) void lstm_scan_s0(
     const short* __restrict__ xg,
     const unsigned char* __restrict__ whh8,
     unsigned char* __restrict__ hg8,
     float* __restrict__ c_state,
     unsigned char* __restrict__ h_state,
     int first, int CT)
{
  __shared__ unsigned char hbuf[8704];
  int wg = blockIdx.x;
  int dir = wg >> 3, r = wg & 7;
  int tid = threadIdx.x, w = tid >> 6, lane = tid & 63, lm = lane & 15, lq = lane >> 4;
  const unsigned char* __restrict__ whhd = whh8 + (long)dir*262144;

  float c[4];
  if(first){
    for(int i=tid; i<8704; i+=1024) hbuf[i] = 0;
#pragma unroll
    for(int i=0;i<4;i++) c[i] = 0.f;
  } else {
    int row = tid >> 6, col = tid & 63;
    *(int*)(hbuf + row*272 + col*4) = *(const int*)(h_state + wg*4096 + row*256 + col*4);
#pragma unroll
    for(int i=0;i<4;i++) c[i] = c_state[(wg*1024 + tid)*4 + i];
  }
  __syncthreads();

  int p = 0;
  for(int tl=0; tl<CT; tl++){
    i4v Bs[16];
#pragma unroll
    for(int grp=0; grp<4; grp++)
#pragma unroll
      for(int kp=0; kp<4; kp++){
        int ct = grp*16 + w;
        Bs[grp*4+kp] = *(const i4v*)(whhd + ((ct*4+kp)<<10) + lane*16);
      }
    const short* __restrict__ xgt = xg + ((long)dir*CT + tl)*131072 + (long)r*16384 + lane*4;
    short4 xv[4];
#pragma unroll
    for(int grp=0;grp<4;grp++)
      xv[grp] = *(const short4*)(xgt + (grp*16 + w)*256);

    const unsigned char* hb = hbuf + p*4352;
    long A[8];
#pragma unroll
    for(int kk=0;kk<8;kk++)
      A[kk] = *(const long*)(hb + lm*272 + kk*32 + lq*8);

    v4f acc[4];
#pragma unroll
    for(int grp=0;grp<4;grp++) acc[grp] = (v4f){0.f,0.f,0.f,0.f};
#pragma unroll
    for(int grp=0;grp<4;grp++)
#pragma unroll
      for(int kk=0;kk<8;kk++){
        union { i4v v; long l[2]; } u;
        u.v = Bs[grp*4 + (kk>>1)];
        acc[grp] = __builtin_amdgcn_mfma_f32_16x16x32_fp8_fp8(A[kk], u.l[kk&1], acc[grp], 0,0,0);
      }

    unsigned char* hnew = hbuf + (p^1)*4352;
    {
      int d = 16*w + lm;
      float hv[4];
#pragma unroll
      for(int rr=0;rr<4;rr++){
        float ig = acc[0][rr] + sel4(xv[0], rr);
        float fg = acc[1][rr] + sel4(xv[1], rr);
        float gg = acc[2][rr] + sel4(xv[2], rr);
        float og = acc[3][rr] + sel4(xv[3], rr);
        float cn = sigm(fg)*c[rr] + sigm(ig)*tanh_(gg);
        c[rr] = cn;
        hv[rr] = sigm(og)*tanh_(cn);
      }
      int packed = __builtin_amdgcn_cvt_pk_fp8_f32(hv[0], hv[1], 0, 0);
      packed = __builtin_amdgcn_cvt_pk_fp8_f32(hv[2], hv[3], packed, 1);
#pragma unroll
      for(int rr=0;rr<4;rr++)
        hnew[(lq*4+rr)*272 + d] = (unsigned char)((packed >> (8*rr)) & 0xff);
    }
    __syncthreads();
    {
      int row = tid >> 6, col = tid & 63;
      *(int*)(hg8 + ((long)dir*CT + tl)*32768 + (r*16+row)*256 + col*4)
        = *(const int*)(hnew + row*272 + col*4);
    }
    p ^= 1;
  }
  {
    int row = tid >> 6, col = tid & 63;
    const unsigned char* hb = hbuf + p*4352;
    *(int*)(h_state + wg*4096 + row*256 + col*4) = *(const int*)(hb + row*272 + col*4);
#pragma unroll
    for(int i=0;i<4;i++) c_state[(wg*1024 + tid)*4 + i] = c[i];
  }
}

// ---------------------------------------------------------------------------
// emiss_partial (unchanged)
// ---------------------------------------------------------------------------
__global__ void emiss_partial(const unsigned char* hg8, const float* lin_w,
                              float* em, int t_base, int CT)
{
  int dir = blockIdx.y;
  int wv  = blockIdx.x*4 + (threadIdx.x >> 6);
  int lane = threadIdx.x & 63;
  int tl = wv >> 7, b = wv & 127;
  int s = dir ? (511 - (t_base + tl)) : (t_base + tl);
  int v = *(const int*)(hg8 + ((long)dir*CT + tl)*32768 + b*256 + lane*4);
  v2f lo = __builtin_amdgcn_cvt_pk_f32_fp8(v, 0);
  v2f hi = __builtin_amdgcn_cvt_pk_f32_fp8(v, 1);
  float x0 = lo[0], x1 = lo[1], x2 = hi[0], x3 = hi[1];
  const float* wbase = lin_w + dir*256 + lane*4;
  float part[9];
#pragma unroll
  for(int j=0;j<9;j++){
    float4 wf = *(const float4*)(wbase + j*512);
    part[j] = x0*wf.x + x1*wf.y + x2*wf.z + x3*wf.w;
  }
#pragma unroll
  for(int j=0;j<9;j++){
    float vv = part[j];
#pragma unroll
    for(int off=32; off>0; off>>=1) vv += __shfl_down(vv, off);
    if(lane == 0) em[((long)b*512 + s)*9 + j] += vv;
  }
}

// ---------------------------------------------------------------------------
// CRF (unchanged)
// ---------------------------------------------------------------------------
__global__ void crf_kernel(const float* em, const int* y, const unsigned char* maskb,
                           const float* st, const float* en, const float* tr,
                           const float* lin_b, float* out)
{
  int b = blockIdx.x;
  int lane = threadIdx.x;
  bool isb = (maskb[1] != 0);
  int len = 0;
  for(int k=lane; k<512; k+=64){
    unsigned char mv = isb ? maskb[b*512 + k] : maskb[((long)(b*512 + k))*4];
    len += (mv != 0);
  }
#pragma unroll
  for(int off=32; off>0; off>>=1) len += __shfl_xor(len, off);

  const int* yb = y + b*512;
  float np = 0.f;
  for(int t=lane; t<512; t+=64){
    if(t >= 1 && t < len){
      int yp = yb[t-1], yt = yb[t];
      np += tr[yp*9 + yt] + em[((long)b*512 + t)*9 + yt] + lin_b[yt];
    }
  }
#pragma unroll
  for(int off=32; off>0; off>>=1) np += __shfl_xor(np, off);

  int j = lane;
  float alpha = -1e30f;
  float trc[9];
  float lb = (j < 9) ? lin_b[j] : 0.f;
  if(j < 9){
    alpha = st[j] + em[(long)b*512*9 + j] + lb;
#pragma unroll
    for(int i=0;i<9;i++) trc[i] = tr[i*9 + j];
  }
  for(int t=1; t<len; t++){
    float av[9];
#pragma unroll
    for(int i=0;i<9;i++) av[i] = __shfl(alpha, i);
    if(j < 9){
      float m = av[0] + trc[0];
#pragma unroll
      for(int i=1;i<9;i++) m = fmaxf(m, av[i] + trc[i]);
      float ssum = 0.f;
#pragma unroll
      for(int i=0;i<9;i++) ssum += __expf(av[i] + trc[i] - m);
      alpha = m + __logf(ssum) + em[((long)b*512 + t)*9 + j] + lb;
    }
  }
  float aj = (j < 9) ? (alpha + en[j]) : -1e30f;
  float mm = aj;
#pragma unroll
  for(int off=32; off>0; off>>=1) mm = fmaxf(mm, __shfl_xor(mm, off));
  float ee = (j < 9) ? __expf(aj - mm) : 0.f;
#pragma unroll
  for(int off=32; off>0; off>>=1) ee += __shfl_xor(ee, off);
  float den = mm + __logf(ee);
  if(lane == 0){
    int y0 = yb[0];
    float num = np + st[y0] + em[(long)b*512*9 + y0] + lin_b[y0] + en[yb[len-1]];
    atomicAdd(out, num - den);
  }
}

// ---------------------------------------------------------------------------
extern "C" void kernel_launch(void* const* d_in, const int* in_sizes, int n_in,
                              void* d_out, int out_size, void* d_ws, size_t ws_size,
                              hipStream_t stream)
{
  (void)in_sizes; (void)n_in; (void)out_size;
  const int*   X    = (const int*)d_in[0];
  const int*   y    = (const int*)d_in[1];
  const unsigned char* maskb = (const unsigned char*)d_in[2];
  const float* emb  = (const float*)d_in[3];
  const float* wihf = (const float*)d_in[4];
  const float* whhf = (const float*)d_in[5];
  const float* bihf = (const float*)d_in[6];
  const float* bhhf = (const float*)d_in[7];
  const float* wihb = (const float*)d_in[8];
  const float* whhb = (const float*)d_in[9];
  const float* bihb = (const float*)d_in[10];
  const float* bhhb = (const float*)d_in[11];
  const float* lin_w= (const float*)d_in[12];
  const float* lin_b= (const float*)d_in[13];
  const float* st   = (const float*)d_in[14];
  const float* en   = (const float*)d_in[15];
  const float* tr   = (const float*)d_in[16];

  // ws layout (bytes)
  const long FIXED = 4595712L;
  long CT = 256;
  while (CT > 16 && FIXED + CT*589824L > (long)ws_size) CT >>= 1;
  int NC = (int)(512 / CT);

  char* ws = (char*)d_ws;
  short*         wswz = (short*)(ws);                    // 1,048,576 B
  unsigned char* whh8 = (unsigned char*)(ws + 1048576L); //   524,288 B (fallback)
  unsigned char* whh4 = (unsigned char*)(ws + 1572864L); //   262,144 B (MXFP4)
  int2*          whsc = (int2*)(ws + 1835008L);          //    65,536 B (scales)
  float*         cb   = (float*)(ws + 1900544L);         //     8,192 B
  float*         cst  = (float*)(ws + 1908736L);         //   262,144 B
  unsigned char* hst  = (unsigned char*)(ws + 2170880L); //    65,536 B
  float*         em   = (float*)(ws + 2236416L);         // 2,359,296 B
  short*         xg   = (short*)(ws + 4595712L);         // CT*524,288 B
  unsigned char* hg8  = (unsigned char*)(ws + 4595712L + CT*524288L); // CT*65,536 B

  const int LDS4 = 131072 + 8704;      // 139,776 B
  bool big = (hipFuncSetAttribute(reinterpret_cast<const void*>(&lstm_scan4),
              hipFuncAttributeMaxDynamicSharedMemorySize, LDS4) == hipSuccess);

  prep_kernel<<<512, 256, 0, stream>>>(wihf, whhf, wihb, whhb,
                                       bihf, bhhf, bihb, bhhb,
                                       wswz, whh4, whsc, whh8, cb, em, (float*)d_out);
  for(int ck=0; ck<NC; ck++){
    int tb = ck*(int)CT;
    xg_gemm<<<dim3(2*(int)CT, 2), 256, 0, stream>>>(X, emb, wswz, cb, xg, tb, (int)CT);
    if(big)
      lstm_scan4<<<16, 1024, LDS4, stream>>>(xg, whh4, whsc, hg8, cst, hst, ck==0 ? 1 : 0, (int)CT);
    else
      lstm_scan_s0<<<16, 1024, 0, stream>>>(xg, whh8, hg8, cst, hst, ck==0 ? 1 : 0, (int)CT);
    emiss_partial<<<dim3(32*(int)CT, 2), 256, 0, stream>>>(hg8, lin_w, em, tb, (int)CT);
  }
  crf_kernel<<<128, 64, 0, stream>>>(em, y, maskb, st, en, tr, lin_b, (float*)d_out);
}